// Round 1
// 453.630 us; speedup vs baseline: 1.0044x; 1.0044x over previous
//
#include <hip/hip_runtime.h>
#include <stdint.h>

// VQ-VAE forward on MI355X — bf16-MFMA fast path + fp64 rescue for exact np argmin.
// Round 9: (1) rescue restructured from 8 rows/group (acc[4][8]=64 VGPRs -> spill,
// 127us, 40 active blocks) to 2 rows/group (acc=16 VGPRs, ~160 active blocks);
// accumulation order per code is bit-identical to round 8. (2) dist2 grid
// flattened with XCD-aware swizzle: 8 column-blocks of each A row-panel land on
// the same XCD, adjacent in dispatch -> A_hi fetched ~once (32MB) instead of 8x.
//
// z_e: [64, 256, 32, 32] f32 ; emb: [1024, 256] f32
// out: z_q_st (16777216) | loss (1) | perplexity (1) | idx (65536, as float)
//
// Big scratch in d_out's z_q region (overwritten by epilogue last):
//   out bytes [0, 32MB)       A_hi  bf16[65536][256]  (transposed z_e)
//   out bytes [32MB, 40MB)    top2  u64[8][65536][2]
// ws layout (bytes):
//   [0,      4096)    enorm f32[1024]      [4096,   266240)  xnorm f32[65536]
//   [266240, 528384)  fidx  i32[65536]     [528384, 532480)  counts i32[1024]
//   [532480, 532484)  loss_sum             [532484, 532488)  amb_count
//   [532488, 794632)  amb i32[65536]
//   [794752, 1319040) B_hi bf16[1024][256]
//   [1319040,2367616) embT f32[256][1024]

#define D_DIM   256
#define K_CODES 1024
#define N_ROWS  65536
#define N_ELEM  16777216
#define IDX_OFF 16777218
#define FLAG_MARGIN 4.0e-4f
#define AMB_CAP 65536

typedef short short8 __attribute__((ext_vector_type(8)));
typedef float f32x4  __attribute__((ext_vector_type(4)));

__device__ __forceinline__ unsigned int mono(float s) {
    unsigned int u = __float_as_uint(s);
    return (u & 0x80000000u) ? ~u : (u | 0x80000000u);
}
__device__ __forceinline__ float unmono(unsigned int u) {
    return __uint_as_float((u & 0x80000000u) ? (u & 0x7FFFFFFFu) : ~u);
}
__device__ __forceinline__ unsigned short bf16_rne(float x) {
    unsigned int u = __float_as_uint(x);
    return (unsigned short)((u + 0x7FFFu + ((u >> 16) & 1u)) >> 16);
}
__device__ __forceinline__ void gld16(const void* g, void* l) {
    __builtin_amdgcn_global_load_lds(
        (const __attribute__((address_space(1))) unsigned int*)g,
        (__attribute__((address_space(3))) unsigned int*)l, 16, 0, 0);
}

// ---- A-prep: transpose z_e -> A_hi bf16 row-major; np-pairwise xnorm ----
__launch_bounds__(128)
__global__ void a_prep_kernel(const float* __restrict__ z_e,
                              unsigned short* __restrict__ A_hi,
                              float* __restrict__ xnorm) {
#pragma clang fp contract(off)
    __shared__ float T[32][257];
    __shared__ float H[32][2];
    const int tid = threadIdx.x;
    const int bx = blockIdx.x;                 // 2048 blocks
    const int b = bx >> 5, hw0 = (bx & 31) << 5;
    const float* zb = z_e + (size_t)b * 262144 + hw0;
    #pragma unroll 4
    for (int it = 0; it < 16; ++it) {
        int flat = it * 128 + tid;             // 2048 float4
        int d = flat >> 3;
        int hw4 = (flat & 7) << 2;
        float4 v = *(const float4*)(zb + (size_t)d * 1024 + hw4);
        T[hw4 + 0][d] = v.x; T[hw4 + 1][d] = v.y;
        T[hw4 + 2][d] = v.z; T[hw4 + 3][d] = v.w;
    }
    __syncthreads();
    if (tid < 64) {                            // np pairwise tree per 128-half
        int row = tid >> 1, h = tid & 1;
        const float* q = &T[row][h * 128];
        float r[8];
        #pragma unroll
        for (int j = 0; j < 8; ++j) { float x = q[j]; r[j] = x * x; }
        for (int i = 8; i < 128; i += 8)
            #pragma unroll
            for (int j = 0; j < 8; ++j) { float x = q[i + j]; r[j] = r[j] + x * x; }
        H[row][h] = ((r[0] + r[1]) + (r[2] + r[3])) + ((r[4] + r[5]) + (r[6] + r[7]));
    }
    __syncthreads();
    if (tid < 32) xnorm[b * 1024 + hw0 + tid] = H[tid][0] + H[tid][1];
    {   // convert: thread -> (row, 64-d segment)
        int row = tid >> 2, seg = tid & 3;
        const float* src = &T[row][seg * 64];
        unsigned short* dst = A_hi + ((size_t)(b * 1024 + hw0 + row) * 256 + seg * 64);
        #pragma unroll
        for (int c = 0; c < 8; ++c) {
            unsigned int ub[4];
            #pragma unroll
            for (int p = 0; p < 4; ++p) {
                unsigned int lo = bf16_rne(src[c * 8 + 2 * p]);
                unsigned int hi = bf16_rne(src[c * 8 + 2 * p + 1]);
                ub[p] = lo | (hi << 16);
            }
            *(uint4*)(dst + c * 8) = make_uint4(ub[0], ub[1], ub[2], ub[3]);
        }
    }
}

// ---- emb-prep: np-pairwise enorm + B_hi bf16 + embT fp32 (d-major) ----
__launch_bounds__(256)
__global__ void emb_prep_kernel(const float* __restrict__ emb,
                                float* __restrict__ enorm,
                                unsigned short* __restrict__ B_hi,
                                float* __restrict__ embT) {
#pragma clang fp contract(off)
    const int k = blockIdx.x * 256 + threadIdx.x;
    const float* p = emb + (size_t)k * D_DIM;
    float half[2];
    #pragma unroll
    for (int h = 0; h < 2; ++h) {
        const float* q = p + h * 128;
        float r[8];
        #pragma unroll
        for (int j = 0; j < 8; ++j) { float x = q[j]; r[j] = x * x; }
        for (int i = 8; i < 128; i += 8)
            #pragma unroll
            for (int j = 0; j < 8; ++j) { float x = q[i + j]; r[j] = r[j] + x * x; }
        half[h] = ((r[0] + r[1]) + (r[2] + r[3])) + ((r[4] + r[5]) + (r[6] + r[7]));
    }
    enorm[k] = half[0] + half[1];
    unsigned int* dst = (unsigned int*)(B_hi + (size_t)k * D_DIM);
    for (int d = 0; d < 128; ++d) {
        unsigned int lo = bf16_rne(p[2 * d]), hi = bf16_rne(p[2 * d + 1]);
        dst[d] = lo | (hi << 16);
    }
    for (int d = 0; d < D_DIM; ++d)            // coalesced: consecutive k per lane
        embT[(size_t)d * K_CODES + k] = p[d];
}

// ---- dist2: bf16 MFMA GEMM, 128x128 tile, per-row top-2, XCD-swizzled grid ----
__launch_bounds__(256, 2)
__global__ void dist2_kernel(const unsigned short* __restrict__ A_hi,
                             const unsigned short* __restrict__ B_hi,
                             const float* __restrict__ xnorm,
                             const float* __restrict__ enorm,
                             unsigned long long* __restrict__ top2) {
    __shared__ __align__(16) char smem[16384];            // As 8KB | Bs 8KB
    short* As = (short*)smem;
    short* Bs = (short*)(smem + 8192);
    unsigned long long* red = (unsigned long long*)smem;  // overlay [128][2][2]

    const int tid  = threadIdx.x;
    const int lane = tid & 63, w = tid >> 6;
    const int quad = lane >> 4, l16 = lane & 15;
    const int wr = w >> 1, wc = w & 1;

    // XCD-aware swizzle: 4096 blocks, bid&7 = XCD. Each XCD owns a contiguous
    // 64-row-panel range; the 8 column-blocks of a panel are adjacent in
    // dispatch order on the SAME XCD -> A panel is L2-hot, fetched ~once.
    const int bid = blockIdx.x;
    const int xcd = bid & 7;
    const int q   = bid >> 3;                  // 0..511
    const int rb  = xcd * 64 + (q >> 3);       // row-block 0..511
    const int cb  = q & 7;                     // col-block 0..7
    const int row0 = rb * 128;
    const int n0   = cb * 128;

    f32x4 acc[4][4];
    #pragma unroll
    for (int i = 0; i < 4; ++i)
        #pragma unroll
        for (int j = 0; j < 4; ++j) acc[i][j] = (f32x4){0.f, 0.f, 0.f, 0.f};

    const int c0 = 2 * w, c1 = 2 * w + 1;
    const int mr = lane >> 2, kq = (lane & 3) * 8;
    const unsigned short* gA0 = A_hi + ((size_t)(row0 + c0 * 16 + mr) * 256 + kq);
    const unsigned short* gA1 = A_hi + ((size_t)(row0 + c1 * 16 + mr) * 256 + kq);
    const unsigned short* gB0 = B_hi + ((size_t)(n0 + c0 * 16 + mr) * 256 + kq);
    const unsigned short* gB1 = B_hi + ((size_t)(n0 + c1 * 16 + mr) * 256 + kq);
    char* lA0 = smem + c0 * 1024;
    char* lA1 = smem + c1 * 1024;
    char* lB0 = smem + 8192 + c0 * 1024;
    char* lB1 = smem + 8192 + c1 * 1024;

    for (int s = 0; s < 8; ++s) {
        gld16(gA0, lA0); gld16(gA1, lA1);
        gld16(gB0, lB0); gld16(gB1, lB1);
        gA0 += 32; gA1 += 32; gB0 += 32; gB1 += 32;
        __syncthreads();
        short8 af[4], bf[4];
        #pragma unroll
        for (int i = 0; i < 4; ++i)
            af[i] = *(const short8*)(As + (wr * 64 + i * 16 + l16) * 32 + quad * 8);
        #pragma unroll
        for (int j = 0; j < 4; ++j)
            bf[j] = *(const short8*)(Bs + (wc * 64 + j * 16 + l16) * 32 + quad * 8);
        #pragma unroll
        for (int i = 0; i < 4; ++i)
            #pragma unroll
            for (int j = 0; j < 4; ++j)
                acc[i][j] = __builtin_amdgcn_mfma_f32_16x16x32_bf16(af[i], bf[j], acc[i][j], 0, 0, 0);
        __syncthreads();
    }

    float enj[4];
    #pragma unroll
    for (int j = 0; j < 4; ++j) enj[j] = enorm[n0 + wc * 64 + j * 16 + l16];

    #pragma unroll
    for (int i = 0; i < 4; ++i) {
        #pragma unroll
        for (int r = 0; r < 4; ++r) {
            int rowl = wr * 64 + i * 16 + quad * 4 + r;
            float xn = xnorm[row0 + rowl];
            unsigned long long p1 = ~0ull, p2 = ~0ull;
            #pragma unroll
            for (int j = 0; j < 4; ++j) {
                int n = n0 + wc * 64 + j * 16 + l16;
                float t1 = xn + enj[j];
                float sc = t1 - 2.0f * acc[i][j][r];
                unsigned long long p = ((unsigned long long)mono(sc) << 32) | (unsigned int)n;
                if (p < p1) { p2 = p1; p1 = p; } else if (p < p2) p2 = p;
            }
            #pragma unroll
            for (int m = 1; m < 16; m <<= 1) {
                unsigned long long q1 = __shfl_xor(p1, m, 16);
                unsigned long long q2 = __shfl_xor(p2, m, 16);
                if (q1 < p1) { p2 = (p1 < q2) ? p1 : q2; p1 = q1; }
                else         { p2 = (p2 < q1) ? p2 : q1; }
            }
            if (l16 == 0) {
                red[(rowl * 2 + wc) * 2 + 0] = p1;
                red[(rowl * 2 + wc) * 2 + 1] = p2;
            }
        }
    }
    __syncthreads();
    if (tid < 128) {
        unsigned long long p1 = red[(tid * 2 + 0) * 2 + 0];
        unsigned long long p2 = red[(tid * 2 + 0) * 2 + 1];
        unsigned long long q1 = red[(tid * 2 + 1) * 2 + 0];
        unsigned long long q2 = red[(tid * 2 + 1) * 2 + 1];
        if (q1 < p1) { p2 = (p1 < q2) ? p1 : q2; p1 = q1; }
        else         { p2 = (p2 < q1) ? p2 : q1; }
        size_t o = ((size_t)cb * N_ROWS + row0 + tid) * 2;
        top2[o + 0] = p1;
        top2[o + 1] = p2;
    }
}

__global__ void resolve_kernel(const unsigned long long* __restrict__ top2,
                               int* __restrict__ fidx,
                               int* __restrict__ amb,
                               int* __restrict__ amb_count) {
    int row = blockIdx.x * 256 + threadIdx.x;
    unsigned long long p1 = ~0ull, p2 = ~0ull;
    #pragma unroll
    for (int c = 0; c < 8; ++c) {
        size_t o = ((size_t)c * N_ROWS + row) * 2;
        unsigned long long a = top2[o + 0];
        unsigned long long b = top2[o + 1];
        if (a < p1) { p2 = p1; p1 = a; } else if (a < p2) p2 = a;
        if (b < p1) { p2 = p1; p1 = b; } else if (b < p2) p2 = b;
    }
    fidx[row] = (int)(p1 & 0xFFFFFFFFull);
    float s1 = unmono((unsigned int)(p1 >> 32));
    float s2 = unmono((unsigned int)(p2 >> 32));
    if (s2 - s1 <= FLAG_MARGIN) {
        int slot = atomicAdd(amb_count, 1);
        if (slot < AMB_CAP) amb[slot] = row;
    }
}

// ---- rescue (2 rows/group): thread owns 4 consecutive codes x 2 rows.
// acc = 8 doubles = 16 VGPRs (round 8's acc[4][8]=64 VGPRs spilled: counter
// showed VGPR_Count=68 < accumulator footprint, 9x inflation vs compute floor).
// Per-code accumulation order over d is IDENTICAL to round 8 -> same results.
__launch_bounds__(256)
__global__ void rescue2_kernel(const float* __restrict__ z_e,
                               const float* __restrict__ embT,
                               const float* __restrict__ xnorm,
                               const float* __restrict__ enorm,
                               const int* __restrict__ amb,
                               const int* __restrict__ amb_count,
                               int* __restrict__ fidx) {
    __shared__ float xs[2][256];
    __shared__ int rows[2];
    __shared__ unsigned long long pm[2][257];
    const int tid = threadIdx.x;
    int cnt = *amb_count;
    if (cnt > AMB_CAP) cnt = AMB_CAP;
    if (cnt <= 0) return;
    const int ngroups = (cnt + 1) >> 1;
    for (int g = blockIdx.x; g < ngroups; g += gridDim.x) {
        if (tid < 2) {
            int e = g * 2 + tid;
            rows[tid] = amb[e < cnt ? e : (cnt - 1)];   // pad with dup (benign)
        }
        __syncthreads();
        {   // stage x rows: thread -> (row j, 2 d-elements)
            const int j = tid >> 7, d0 = (tid & 127) * 2;
            const int row = rows[j];
            const int b = row >> 10, hw = row & 1023;
            const float* zp = z_e + (size_t)b * 262144 + hw;
            xs[j][d0 + 0] = zp[(size_t)(d0 + 0) * 1024];
            xs[j][d0 + 1] = zp[(size_t)(d0 + 1) * 1024];
        }
        __syncthreads();

        double a00 = 0.0, a01 = 0.0, a10 = 0.0, a11 = 0.0;
        double a20 = 0.0, a21 = 0.0, a30 = 0.0, a31 = 0.0;
        const float* ep = embT + 4 * tid;
        #pragma unroll 4
        for (int d = 0; d < D_DIM; ++d) {
            float4 ev = *(const float4*)(ep + (size_t)d * K_CODES);
            double xd0 = (double)xs[0][d];
            double xd1 = (double)xs[1][d];
            a00 += xd0 * (double)ev.x; a01 += xd1 * (double)ev.x;
            a10 += xd0 * (double)ev.y; a11 += xd1 * (double)ev.y;
            a20 += xd0 * (double)ev.z; a21 += xd1 * (double)ev.z;
            a30 += xd0 * (double)ev.w; a31 += xd1 * (double)ev.w;
        }

        const float xnr0 = xnorm[rows[0]];
        const float xnr1 = xnorm[rows[1]];
        double r0[4] = {a00, a10, a20, a30};
        double r1[4] = {a01, a11, a21, a31};
        unsigned long long m0 = ~0ull, m1 = ~0ull;
        #pragma unroll
        for (int c = 0; c < 4; ++c) {
            const int k = 4 * tid + c;
            const float en = enorm[k];
            float d0 = (float)r0[c];
            float d1 = (float)r1[c];
            float t0 = xnr0 + en;
            float t1 = xnr1 + en;
            float s0 = t0 - 2.f * d0;
            float s1 = t1 - 2.f * d1;
            unsigned long long p0 = ((unsigned long long)mono(s0) << 32) | (unsigned int)k;
            unsigned long long p1 = ((unsigned long long)mono(s1) << 32) | (unsigned int)k;
            if (p0 < m0) m0 = p0;
            if (p1 < m1) m1 = p1;
        }
        pm[0][tid] = m0;
        pm[1][tid] = m1;
        __syncthreads();
        for (int s = 128; s > 0; s >>= 1) {
            if (tid < s) {
                if (pm[0][tid + s] < pm[0][tid]) pm[0][tid] = pm[0][tid + s];
                if (pm[1][tid + s] < pm[1][tid]) pm[1][tid] = pm[1][tid + s];
            }
            __syncthreads();
        }
        if (tid < 2) fidx[rows[tid]] = (int)(pm[tid][0] & 0xFFFFFFFFull);
        __syncthreads();
    }
}

__global__ void epilogue_kernel(const float* __restrict__ z_e,
                                const float* __restrict__ emb,
                                const int* __restrict__ fidx,
                                float* __restrict__ out,
                                int* __restrict__ counts,
                                float* __restrict__ loss_sum) {
    __shared__ int   kb[64];
    __shared__ float rs[256];
    const int tid = threadIdx.x;
    const int rcb = blockIdx.x;
    const int b   = rcb >> 4;
    const int hw0 = (rcb & 15) << 6;

    if (tid < 64) {
        int k = fidx[rcb * 64 + tid];
        kb[tid] = k;
        out[(size_t)IDX_OFF + (size_t)rcb * 64 + tid] = (float)k;
        atomicAdd(&counts[k], 1);
    }
    __syncthreads();

    const int j = tid & 63, dq = tid >> 6;
    const float* er = emb + (size_t)kb[j] * D_DIM;
    const size_t base = (size_t)b * 262144 + hw0 + j;
    float ls = 0.f;
    #pragma unroll 4
    for (int d = dq; d < D_DIM; d += 4) {
        float zq = er[d];
        size_t off = base + (size_t)d * 1024;
        float x = z_e[off];
        out[off] = zq;
        float df = zq - x;
        ls += df * df;
    }
    rs[tid] = ls;
    __syncthreads();
    for (int s = 128; s > 0; s >>= 1) {
        if (tid < s) rs[tid] += rs[tid + s];
        __syncthreads();
    }
    if (tid == 0) atomicAdd(loss_sum, rs[0]);
}

__global__ void finalize_kernel(const int* __restrict__ counts,
                                const float* __restrict__ loss_sum,
                                float* __restrict__ out) {
    __shared__ float rs[256];
    const int tid = threadIdx.x;
    float s = 0.f;
    for (int k = tid; k < K_CODES; k += 256) {
        float p = (float)counts[k] / 65536.0f;
        s += p * logf(p + 1e-10f);
    }
    rs[tid] = s;
    __syncthreads();
    for (int st = 128; st > 0; st >>= 1) {
        if (tid < st) rs[tid] += rs[tid + st];
        __syncthreads();
    }
    if (tid == 0) {
        out[N_ELEM]     = loss_sum[0] * 1.25f / 16777216.0f;
        out[N_ELEM + 1] = expf(-rs[0]);
    }
}

extern "C" void kernel_launch(void* const* d_in, const int* in_sizes, int n_in,
                              void* d_out, int out_size, void* d_ws, size_t ws_size,
                              hipStream_t stream) {
    const float* z_e = (const float*)d_in[0];
    const float* emb = (const float*)d_in[1];
    float* out = (float*)d_out;
    char*  ws  = (char*)d_ws;

    // big scratch inside d_out (overwritten by epilogue)
    unsigned short*     A_hi = (unsigned short*)d_out;
    unsigned long long* top2 = (unsigned long long*)((char*)d_out + 33554432);

    float*          enorm    = (float*)ws;
    float*          xnorm    = (float*)(ws + 4096);
    int*            fidx     = (int*)(ws + 266240);
    int*            counts   = (int*)(ws + 528384);
    float*          loss_sum = (float*)(ws + 532480);
    int*            amb_cnt  = (int*)(ws + 532484);
    int*            amb      = (int*)(ws + 532488);
    unsigned short* B_hi     = (unsigned short*)(ws + 794752);
    float*          embT     = (float*)(ws + 1319040);

    hipMemsetAsync(counts, 0, 4104, stream);   // counts + loss_sum + amb_count

    a_prep_kernel<<<2048, 128, 0, stream>>>(z_e, A_hi, xnorm);
    emb_prep_kernel<<<K_CODES / 256, 256, 0, stream>>>(emb, enorm, B_hi, embT);
    dist2_kernel<<<4096, 256, 0, stream>>>(A_hi, B_hi, xnorm, enorm, top2);
    resolve_kernel<<<N_ROWS / 256, 256, 0, stream>>>(top2, fidx, amb, amb_cnt);
    rescue2_kernel<<<1024, 256, 0, stream>>>(z_e, embT, xnorm, enorm, amb, amb_cnt, fidx);
    epilogue_kernel<<<N_ROWS / 64, 256, 0, stream>>>(z_e, emb, fidx, out, counts, loss_sum);
    finalize_kernel<<<1, 256, 0, stream>>>(counts, loss_sum, out);
}

// Round 2
// 383.546 us; speedup vs baseline: 1.1879x; 1.1827x over previous
//
#include <hip/hip_runtime.h>
#include <hip/hip_fp16.h>
#include <stdint.h>

// VQ-VAE forward on MI355X — fp16-MFMA fast path + fp64 rescue for exact np argmin.
// Round 10: (1) fast path bf16 -> fp16 with power-of-2 pre-scaling (x*16, e*4096;
// epilogue rescales by 2^-15). fp16 rel err 2^-11 vs bf16 2^-8 -> dist-error
// sigma ~5e-6 vs ~4.2e-5. Scaling keeps all fp16 inputs normal (no denorm-flush
// hazard). (2) FLAG_MARGIN 4e-4 -> 1.5e-4 (>=25 sigma of fp16 path error, vs
// 9.5 sigma safety of the old bf16 margin): ambiguous count ~3300 -> ~1300.
// (3) rescue regrouped to 4 rows/group (16 fp64 accs = 32 VGPRs, static
// indexing): embT L2 restream = cnt/4 MB, one group per block, all parallel.
// Rescue accumulation order per (code,row) is d-ascending — bit-identical to
// round 9. Round-9 lesson: rescue was L2-restream-bound (1.65 GB), not spill.
//
// z_e: [64, 256, 32, 32] f32 ; emb: [1024, 256] f32
// out: z_q_st (16777216) | loss (1) | perplexity (1) | idx (65536, as float)
//
// Big scratch in d_out's z_q region (overwritten by epilogue last):
//   out bytes [0, 32MB)       A_hi  fp16[65536][256]  (transposed z_e, x16)
//   out bytes [32MB, 40MB)    top2  u64[8][65536][2]
// ws layout (bytes):
//   [0,      4096)    enorm f32[1024]      [4096,   266240)  xnorm f32[65536]
//   [266240, 528384)  fidx  i32[65536]     [528384, 532480)  counts i32[1024]
//   [532480, 532484)  loss_sum             [532484, 532488)  amb_count
//   [532488, 794632)  amb i32[65536]
//   [794752, 1319040) B_hi fp16[1024][256] (e*4096)
//   [1319040,2367616) embT f32[256][1024]

#define D_DIM   256
#define K_CODES 1024
#define N_ROWS  65536
#define N_ELEM  16777216
#define IDX_OFF 16777218
#define FLAG_MARGIN 1.5e-4f
#define AMB_CAP 65536
#define A_SCALE 16.0f
#define B_SCALE 4096.0f
#define INV_SCALE2 3.0517578125e-05f   /* 2 / (16*4096) = 2^-15, exact */

typedef short short8 __attribute__((ext_vector_type(8)));
typedef _Float16 half8 __attribute__((ext_vector_type(8)));
typedef float f32x4  __attribute__((ext_vector_type(4)));

__device__ __forceinline__ unsigned int mono(float s) {
    unsigned int u = __float_as_uint(s);
    return (u & 0x80000000u) ? ~u : (u | 0x80000000u);
}
__device__ __forceinline__ float unmono(unsigned int u) {
    return __uint_as_float((u & 0x80000000u) ? (u & 0x7FFFFFFFu) : ~u);
}
__device__ __forceinline__ unsigned short f16_rne(float x) {
    return __half_as_ushort(__float2half(x));   // RNE
}
__device__ __forceinline__ void gld16(const void* g, void* l) {
    __builtin_amdgcn_global_load_lds(
        (const __attribute__((address_space(1))) unsigned int*)g,
        (__attribute__((address_space(3))) unsigned int*)l, 16, 0, 0);
}

// ---- A-prep: transpose z_e -> A_hi fp16(x*16) row-major; np-pairwise xnorm ----
__launch_bounds__(128)
__global__ void a_prep_kernel(const float* __restrict__ z_e,
                              unsigned short* __restrict__ A_hi,
                              float* __restrict__ xnorm) {
#pragma clang fp contract(off)
    __shared__ float T[32][257];
    __shared__ float H[32][2];
    const int tid = threadIdx.x;
    const int bx = blockIdx.x;                 // 2048 blocks
    const int b = bx >> 5, hw0 = (bx & 31) << 5;
    const float* zb = z_e + (size_t)b * 262144 + hw0;
    #pragma unroll 4
    for (int it = 0; it < 16; ++it) {
        int flat = it * 128 + tid;             // 2048 float4
        int d = flat >> 3;
        int hw4 = (flat & 7) << 2;
        float4 v = *(const float4*)(zb + (size_t)d * 1024 + hw4);
        T[hw4 + 0][d] = v.x; T[hw4 + 1][d] = v.y;
        T[hw4 + 2][d] = v.z; T[hw4 + 3][d] = v.w;
    }
    __syncthreads();
    if (tid < 64) {                            // np pairwise tree per 128-half
        int row = tid >> 1, h = tid & 1;
        const float* q = &T[row][h * 128];
        float r[8];
        #pragma unroll
        for (int j = 0; j < 8; ++j) { float x = q[j]; r[j] = x * x; }
        for (int i = 8; i < 128; i += 8)
            #pragma unroll
            for (int j = 0; j < 8; ++j) { float x = q[i + j]; r[j] = r[j] + x * x; }
        H[row][h] = ((r[0] + r[1]) + (r[2] + r[3])) + ((r[4] + r[5]) + (r[6] + r[7]));
    }
    __syncthreads();
    if (tid < 32) xnorm[b * 1024 + hw0 + tid] = H[tid][0] + H[tid][1];
    {   // convert (scaled fp16): thread -> (row, 64-d segment)
        int row = tid >> 2, seg = tid & 3;
        const float* src = &T[row][seg * 64];
        unsigned short* dst = A_hi + ((size_t)(b * 1024 + hw0 + row) * 256 + seg * 64);
        #pragma unroll
        for (int c = 0; c < 8; ++c) {
            unsigned int ub[4];
            #pragma unroll
            for (int p = 0; p < 4; ++p) {
                unsigned int lo = f16_rne(src[c * 8 + 2 * p] * A_SCALE);
                unsigned int hi = f16_rne(src[c * 8 + 2 * p + 1] * A_SCALE);
                ub[p] = lo | (hi << 16);
            }
            *(uint4*)(dst + c * 8) = make_uint4(ub[0], ub[1], ub[2], ub[3]);
        }
    }
}

// ---- emb-prep: np-pairwise enorm + B_hi fp16(e*4096) + embT fp32 (d-major) ----
__launch_bounds__(256)
__global__ void emb_prep_kernel(const float* __restrict__ emb,
                                float* __restrict__ enorm,
                                unsigned short* __restrict__ B_hi,
                                float* __restrict__ embT) {
#pragma clang fp contract(off)
    const int k = blockIdx.x * 256 + threadIdx.x;
    const float* p = emb + (size_t)k * D_DIM;
    float half[2];
    #pragma unroll
    for (int h = 0; h < 2; ++h) {
        const float* q = p + h * 128;
        float r[8];
        #pragma unroll
        for (int j = 0; j < 8; ++j) { float x = q[j]; r[j] = x * x; }
        for (int i = 8; i < 128; i += 8)
            #pragma unroll
            for (int j = 0; j < 8; ++j) { float x = q[i + j]; r[j] = r[j] + x * x; }
        half[h] = ((r[0] + r[1]) + (r[2] + r[3])) + ((r[4] + r[5]) + (r[6] + r[7]));
    }
    enorm[k] = half[0] + half[1];
    unsigned int* dst = (unsigned int*)(B_hi + (size_t)k * D_DIM);
    for (int d = 0; d < 128; ++d) {
        unsigned int lo = f16_rne(p[2 * d] * B_SCALE);
        unsigned int hi = f16_rne(p[2 * d + 1] * B_SCALE);
        dst[d] = lo | (hi << 16);
    }
    for (int d = 0; d < D_DIM; ++d)            // coalesced: consecutive k per lane
        embT[(size_t)d * K_CODES + k] = p[d];
}

// ---- dist2: fp16 MFMA GEMM, 128x128 tile, per-row top-2, XCD-swizzled grid ----
__launch_bounds__(256, 2)
__global__ void dist2_kernel(const unsigned short* __restrict__ A_hi,
                             const unsigned short* __restrict__ B_hi,
                             const float* __restrict__ xnorm,
                             const float* __restrict__ enorm,
                             unsigned long long* __restrict__ top2) {
    __shared__ __align__(16) char smem[16384];            // As 8KB | Bs 8KB
    short* As = (short*)smem;
    short* Bs = (short*)(smem + 8192);
    unsigned long long* red = (unsigned long long*)smem;  // overlay [128][2][2]

    const int tid  = threadIdx.x;
    const int lane = tid & 63, w = tid >> 6;
    const int quad = lane >> 4, l16 = lane & 15;
    const int wr = w >> 1, wc = w & 1;

    // XCD-aware swizzle: 4096 blocks, bid&7 = XCD. Each XCD owns a contiguous
    // 64-row-panel range; the 8 column-blocks of a panel are adjacent in
    // dispatch order on the SAME XCD -> A panel is L2-hot, fetched ~once.
    const int bid = blockIdx.x;
    const int xcd = bid & 7;
    const int q   = bid >> 3;                  // 0..511
    const int rb  = xcd * 64 + (q >> 3);       // row-block 0..511
    const int cb  = q & 7;                     // col-block 0..7
    const int row0 = rb * 128;
    const int n0   = cb * 128;

    f32x4 acc[4][4];
    #pragma unroll
    for (int i = 0; i < 4; ++i)
        #pragma unroll
        for (int j = 0; j < 4; ++j) acc[i][j] = (f32x4){0.f, 0.f, 0.f, 0.f};

    const int c0 = 2 * w, c1 = 2 * w + 1;
    const int mr = lane >> 2, kq = (lane & 3) * 8;
    const unsigned short* gA0 = A_hi + ((size_t)(row0 + c0 * 16 + mr) * 256 + kq);
    const unsigned short* gA1 = A_hi + ((size_t)(row0 + c1 * 16 + mr) * 256 + kq);
    const unsigned short* gB0 = B_hi + ((size_t)(n0 + c0 * 16 + mr) * 256 + kq);
    const unsigned short* gB1 = B_hi + ((size_t)(n0 + c1 * 16 + mr) * 256 + kq);
    char* lA0 = smem + c0 * 1024;
    char* lA1 = smem + c1 * 1024;
    char* lB0 = smem + 8192 + c0 * 1024;
    char* lB1 = smem + 8192 + c1 * 1024;

    for (int s = 0; s < 8; ++s) {
        gld16(gA0, lA0); gld16(gA1, lA1);
        gld16(gB0, lB0); gld16(gB1, lB1);
        gA0 += 32; gA1 += 32; gB0 += 32; gB1 += 32;
        __syncthreads();
        half8 af[4], bf[4];
        #pragma unroll
        for (int i = 0; i < 4; ++i)
            af[i] = *(const half8*)(As + (wr * 64 + i * 16 + l16) * 32 + quad * 8);
        #pragma unroll
        for (int j = 0; j < 4; ++j)
            bf[j] = *(const half8*)(Bs + (wc * 64 + j * 16 + l16) * 32 + quad * 8);
        #pragma unroll
        for (int i = 0; i < 4; ++i)
            #pragma unroll
            for (int j = 0; j < 4; ++j)
                acc[i][j] = __builtin_amdgcn_mfma_f32_16x16x32_f16(af[i], bf[j], acc[i][j], 0, 0, 0);
        __syncthreads();
    }

    float enj[4];
    #pragma unroll
    for (int j = 0; j < 4; ++j) enj[j] = enorm[n0 + wc * 64 + j * 16 + l16];

    #pragma unroll
    for (int i = 0; i < 4; ++i) {
        #pragma unroll
        for (int r = 0; r < 4; ++r) {
            int rowl = wr * 64 + i * 16 + quad * 4 + r;
            float xn = xnorm[row0 + rowl];
            unsigned long long p1 = ~0ull, p2 = ~0ull;
            #pragma unroll
            for (int j = 0; j < 4; ++j) {
                int n = n0 + wc * 64 + j * 16 + l16;
                float t1 = xn + enj[j];
                float sc = t1 - acc[i][j][r] * INV_SCALE2;
                unsigned long long p = ((unsigned long long)mono(sc) << 32) | (unsigned int)n;
                if (p < p1) { p2 = p1; p1 = p; } else if (p < p2) p2 = p;
            }
            #pragma unroll
            for (int m = 1; m < 16; m <<= 1) {
                unsigned long long q1 = __shfl_xor(p1, m, 16);
                unsigned long long q2 = __shfl_xor(p2, m, 16);
                if (q1 < p1) { p2 = (p1 < q2) ? p1 : q2; p1 = q1; }
                else         { p2 = (p2 < q1) ? p2 : q1; }
            }
            if (l16 == 0) {
                red[(rowl * 2 + wc) * 2 + 0] = p1;
                red[(rowl * 2 + wc) * 2 + 1] = p2;
            }
        }
    }
    __syncthreads();
    if (tid < 128) {
        unsigned long long p1 = red[(tid * 2 + 0) * 2 + 0];
        unsigned long long p2 = red[(tid * 2 + 0) * 2 + 1];
        unsigned long long q1 = red[(tid * 2 + 1) * 2 + 0];
        unsigned long long q2 = red[(tid * 2 + 1) * 2 + 1];
        if (q1 < p1) { p2 = (p1 < q2) ? p1 : q2; p1 = q1; }
        else         { p2 = (p2 < q1) ? p2 : q1; }
        size_t o = ((size_t)cb * N_ROWS + row0 + tid) * 2;
        top2[o + 0] = p1;
        top2[o + 1] = p2;
    }
}

__global__ void resolve_kernel(const unsigned long long* __restrict__ top2,
                               int* __restrict__ fidx,
                               int* __restrict__ amb,
                               int* __restrict__ amb_count) {
    int row = blockIdx.x * 256 + threadIdx.x;
    unsigned long long p1 = ~0ull, p2 = ~0ull;
    #pragma unroll
    for (int c = 0; c < 8; ++c) {
        size_t o = ((size_t)c * N_ROWS + row) * 2;
        unsigned long long a = top2[o + 0];
        unsigned long long b = top2[o + 1];
        if (a < p1) { p2 = p1; p1 = a; } else if (a < p2) p2 = a;
        if (b < p1) { p2 = p1; p1 = b; } else if (b < p2) p2 = b;
    }
    fidx[row] = (int)(p1 & 0xFFFFFFFFull);
    float s1 = unmono((unsigned int)(p1 >> 32));
    float s2 = unmono((unsigned int)(p2 >> 32));
    if (s2 - s1 <= FLAG_MARGIN) {
        int slot = atomicAdd(amb_count, 1);
        if (slot < AMB_CAP) amb[slot] = row;
    }
}

// ---- rescue (4 rows/group): thread owns 4 consecutive codes x 4 rows.
// acc = 16 doubles = 32 VGPRs, all statically indexed (full unroll) -> registers.
// embT stream amortized 4 rows per 1MB pass; per-(code,row) accumulation order
// over d is IDENTICAL to rounds 8/9 -> bit-identical rescue results.
__launch_bounds__(256)
__global__ void rescue4_kernel(const float* __restrict__ z_e,
                               const float* __restrict__ embT,
                               const float* __restrict__ xnorm,
                               const float* __restrict__ enorm,
                               const int* __restrict__ amb,
                               const int* __restrict__ amb_count,
                               int* __restrict__ fidx) {
    __shared__ float xs[4][256];
    __shared__ int rows[4];
    __shared__ unsigned long long pm[4][257];
    const int tid = threadIdx.x;
    int cnt = *amb_count;
    if (cnt > AMB_CAP) cnt = AMB_CAP;
    if (cnt <= 0) return;
    const int ngroups = (cnt + 3) >> 2;
    for (int g = blockIdx.x; g < ngroups; g += gridDim.x) {
        if (tid < 4) {
            int e = g * 4 + tid;
            rows[tid] = amb[e < cnt ? e : (cnt - 1)];   // pad with dup (benign)
        }
        __syncthreads();
        {   // stage x rows: thread -> (row j, 4 d-elements)
            const int j = tid >> 6, d0 = (tid & 63) * 4;
            const int row = rows[j];
            const int b = row >> 10, hw = row & 1023;
            const float* zp = z_e + (size_t)b * 262144 + hw;
            #pragma unroll
            for (int i = 0; i < 4; ++i)
                xs[j][d0 + i] = zp[(size_t)(d0 + i) * 1024];
        }
        __syncthreads();

        double acc[4][4];                       // [code c][row j], static idx only
        #pragma unroll
        for (int c = 0; c < 4; ++c)
            #pragma unroll
            for (int j = 0; j < 4; ++j) acc[c][j] = 0.0;

        const float* ep = embT + 4 * tid;
        #pragma unroll 2
        for (int d = 0; d < D_DIM; ++d) {
            float4 ev = *(const float4*)(ep + (size_t)d * K_CODES);
            double e0 = (double)ev.x, e1 = (double)ev.y;
            double e2 = (double)ev.z, e3 = (double)ev.w;
            double x0 = (double)xs[0][d], x1 = (double)xs[1][d];
            double x2 = (double)xs[2][d], x3 = (double)xs[3][d];
            acc[0][0] += x0 * e0; acc[0][1] += x1 * e0; acc[0][2] += x2 * e0; acc[0][3] += x3 * e0;
            acc[1][0] += x0 * e1; acc[1][1] += x1 * e1; acc[1][2] += x2 * e1; acc[1][3] += x3 * e1;
            acc[2][0] += x0 * e2; acc[2][1] += x1 * e2; acc[2][2] += x2 * e2; acc[2][3] += x3 * e2;
            acc[3][0] += x0 * e3; acc[3][1] += x1 * e3; acc[3][2] += x2 * e3; acc[3][3] += x3 * e3;
        }

        float xnr[4];
        #pragma unroll
        for (int j = 0; j < 4; ++j) xnr[j] = xnorm[rows[j]];

        unsigned long long mm[4] = {~0ull, ~0ull, ~0ull, ~0ull};
        #pragma unroll
        for (int c = 0; c < 4; ++c) {
            const int k = 4 * tid + c;
            const float en = enorm[k];
            #pragma unroll
            for (int j = 0; j < 4; ++j) {
                float dv = (float)acc[c][j];
                float t = xnr[j] + en;
                float s = t - 2.f * dv;
                unsigned long long p = ((unsigned long long)mono(s) << 32) | (unsigned int)k;
                if (p < mm[j]) mm[j] = p;
            }
        }
        #pragma unroll
        for (int j = 0; j < 4; ++j) pm[j][tid] = mm[j];
        __syncthreads();
        for (int s = 128; s > 0; s >>= 1) {
            if (tid < s) {
                #pragma unroll
                for (int j = 0; j < 4; ++j)
                    if (pm[j][tid + s] < pm[j][tid]) pm[j][tid] = pm[j][tid + s];
            }
            __syncthreads();
        }
        if (tid < 4) fidx[rows[tid]] = (int)(pm[tid][0] & 0xFFFFFFFFull);
        __syncthreads();
    }
}

__global__ void epilogue_kernel(const float* __restrict__ z_e,
                                const float* __restrict__ emb,
                                const int* __restrict__ fidx,
                                float* __restrict__ out,
                                int* __restrict__ counts,
                                float* __restrict__ loss_sum) {
    __shared__ int   kb[64];
    __shared__ float rs[256];
    const int tid = threadIdx.x;
    const int rcb = blockIdx.x;
    const int b   = rcb >> 4;
    const int hw0 = (rcb & 15) << 6;

    if (tid < 64) {
        int k = fidx[rcb * 64 + tid];
        kb[tid] = k;
        out[(size_t)IDX_OFF + (size_t)rcb * 64 + tid] = (float)k;
        atomicAdd(&counts[k], 1);
    }
    __syncthreads();

    const int j = tid & 63, dq = tid >> 6;
    const float* er = emb + (size_t)kb[j] * D_DIM;
    const size_t base = (size_t)b * 262144 + hw0 + j;
    float ls = 0.f;
    #pragma unroll 4
    for (int d = dq; d < D_DIM; d += 4) {
        float zq = er[d];
        size_t off = base + (size_t)d * 1024;
        float x = z_e[off];
        out[off] = zq;
        float df = zq - x;
        ls += df * df;
    }
    rs[tid] = ls;
    __syncthreads();
    for (int s = 128; s > 0; s >>= 1) {
        if (tid < s) rs[tid] += rs[tid + s];
        __syncthreads();
    }
    if (tid == 0) atomicAdd(loss_sum, rs[0]);
}

__global__ void finalize_kernel(const int* __restrict__ counts,
                                const float* __restrict__ loss_sum,
                                float* __restrict__ out) {
    __shared__ float rs[256];
    const int tid = threadIdx.x;
    float s = 0.f;
    for (int k = tid; k < K_CODES; k += 256) {
        float p = (float)counts[k] / 65536.0f;
        s += p * logf(p + 1e-10f);
    }
    rs[tid] = s;
    __syncthreads();
    for (int st = 128; st > 0; st >>= 1) {
        if (tid < st) rs[tid] += rs[tid + st];
        __syncthreads();
    }
    if (tid == 0) {
        out[N_ELEM]     = loss_sum[0] * 1.25f / 16777216.0f;
        out[N_ELEM + 1] = expf(-rs[0]);
    }
}

extern "C" void kernel_launch(void* const* d_in, const int* in_sizes, int n_in,
                              void* d_out, int out_size, void* d_ws, size_t ws_size,
                              hipStream_t stream) {
    const float* z_e = (const float*)d_in[0];
    const float* emb = (const float*)d_in[1];
    float* out = (float*)d_out;
    char*  ws  = (char*)d_ws;

    // big scratch inside d_out (overwritten by epilogue)
    unsigned short*     A_hi = (unsigned short*)d_out;
    unsigned long long* top2 = (unsigned long long*)((char*)d_out + 33554432);

    float*          enorm    = (float*)ws;
    float*          xnorm    = (float*)(ws + 4096);
    int*            fidx     = (int*)(ws + 266240);
    int*            counts   = (int*)(ws + 528384);
    float*          loss_sum = (float*)(ws + 532480);
    int*            amb_cnt  = (int*)(ws + 532484);
    int*            amb      = (int*)(ws + 532488);
    unsigned short* B_hi     = (unsigned short*)(ws + 794752);
    float*          embT     = (float*)(ws + 1319040);

    hipMemsetAsync(counts, 0, 4104, stream);   // counts + loss_sum + amb_count

    a_prep_kernel<<<2048, 128, 0, stream>>>(z_e, A_hi, xnorm);
    emb_prep_kernel<<<K_CODES / 256, 256, 0, stream>>>(emb, enorm, B_hi, embT);
    dist2_kernel<<<4096, 256, 0, stream>>>(A_hi, B_hi, xnorm, enorm, top2);
    resolve_kernel<<<N_ROWS / 256, 256, 0, stream>>>(top2, fidx, amb, amb_cnt);
    rescue4_kernel<<<1024, 256, 0, stream>>>(z_e, embT, xnorm, enorm, amb, amb_cnt, fidx);
    epilogue_kernel<<<N_ROWS / 64, 256, 0, stream>>>(z_e, emb, fidx, out, counts, loss_sum);
    finalize_kernel<<<1, 256, 0, stream>>>(counts, loss_sum, out);
}

// Round 3
// 356.198 us; speedup vs baseline: 1.2791x; 1.0768x over previous
//
#include <hip/hip_runtime.h>
#include <hip/hip_fp16.h>
#include <stdint.h>

// VQ-VAE forward on MI355X — fp16-MFMA fast path + fp64 rescue for exact np argmin.
// Round 11: dist2 restructured from 4096 blocks (128x128 tiles, 8 col-blocks per
// row + top2 global round-trip + resolve kernel) to 512 blocks (128 rows x ALL
// 1024 codes). A-tile (64KB) persists in LDS; B streamed in 8KB chunks; per-lane
// running top-2 held in registers across col-chunks (u64 mono-pack is
// order-independent -> bit-identical results); ONE shfl-reduce per row instead
// of 8; fidx/amb written directly (resolve kernel deleted). LDS staged via
// pre-swizzled global sources (granule q^=((row>>1)&3), an involution) so
// fragment ds_read_b128 drop from 8-way bank conflict (4.47M cycles/dispatch)
// to 2-way (free). Round-10 counters: MfmaUtil 13.5%, VALUBusy 45%, epilogue
// reduce ran 8x per row = dominant VALU load.
//
// z_e: [64, 256, 32, 32] f32 ; emb: [1024, 256] f32
// out: z_q_st (16777216) | loss (1) | perplexity (1) | idx (65536, as float)
//
// Big scratch in d_out's z_q region (overwritten by epilogue last):
//   out bytes [0, 32MB)       A_hi  fp16[65536][256]  (transposed z_e, x16)
// ws layout (bytes):
//   [0,      4096)    enorm f32[1024]      [4096,   266240)  xnorm f32[65536]
//   [266240, 528384)  fidx  i32[65536]     [528384, 532480)  counts i32[1024]
//   [532480, 532484)  loss_sum             [532484, 532488)  amb_count
//   [532488, 794632)  amb i32[65536]
//   [794752, 1319040) B_hi fp16[1024][256] (e*4096)
//   [1319040,2367616) embT f32[256][1024]

#define D_DIM   256
#define K_CODES 1024
#define N_ROWS  65536
#define N_ELEM  16777216
#define IDX_OFF 16777218
#define FLAG_MARGIN 1.5e-4f
#define AMB_CAP 65536
#define A_SCALE 16.0f
#define B_SCALE 4096.0f
#define INV_SCALE2 3.0517578125e-05f   /* 2 / (16*4096) = 2^-15, exact */

typedef short short8 __attribute__((ext_vector_type(8)));
typedef _Float16 half8 __attribute__((ext_vector_type(8)));
typedef float f32x4  __attribute__((ext_vector_type(4)));

__device__ __forceinline__ unsigned int mono(float s) {
    unsigned int u = __float_as_uint(s);
    return (u & 0x80000000u) ? ~u : (u | 0x80000000u);
}
__device__ __forceinline__ float unmono(unsigned int u) {
    return __uint_as_float((u & 0x80000000u) ? (u & 0x7FFFFFFFu) : ~u);
}
__device__ __forceinline__ unsigned short f16_rne(float x) {
    return __half_as_ushort(__float2half(x));   // RNE
}
__device__ __forceinline__ void gld16(const void* g, void* l) {
    __builtin_amdgcn_global_load_lds(
        (const __attribute__((address_space(1))) unsigned int*)g,
        (__attribute__((address_space(3))) unsigned int*)l, 16, 0, 0);
}

// ---- A-prep: transpose z_e -> A_hi fp16(x*16) row-major; np-pairwise xnorm ----
__launch_bounds__(128)
__global__ void a_prep_kernel(const float* __restrict__ z_e,
                              unsigned short* __restrict__ A_hi,
                              float* __restrict__ xnorm) {
#pragma clang fp contract(off)
    __shared__ float T[32][257];
    __shared__ float H[32][2];
    const int tid = threadIdx.x;
    const int bx = blockIdx.x;                 // 2048 blocks
    const int b = bx >> 5, hw0 = (bx & 31) << 5;
    const float* zb = z_e + (size_t)b * 262144 + hw0;
    #pragma unroll 4
    for (int it = 0; it < 16; ++it) {
        int flat = it * 128 + tid;             // 2048 float4
        int d = flat >> 3;
        int hw4 = (flat & 7) << 2;
        float4 v = *(const float4*)(zb + (size_t)d * 1024 + hw4);
        T[hw4 + 0][d] = v.x; T[hw4 + 1][d] = v.y;
        T[hw4 + 2][d] = v.z; T[hw4 + 3][d] = v.w;
    }
    __syncthreads();
    if (tid < 64) {                            // np pairwise tree per 128-half
        int row = tid >> 1, h = tid & 1;
        const float* q = &T[row][h * 128];
        float r[8];
        #pragma unroll
        for (int j = 0; j < 8; ++j) { float x = q[j]; r[j] = x * x; }
        for (int i = 8; i < 128; i += 8)
            #pragma unroll
            for (int j = 0; j < 8; ++j) { float x = q[i + j]; r[j] = r[j] + x * x; }
        H[row][h] = ((r[0] + r[1]) + (r[2] + r[3])) + ((r[4] + r[5]) + (r[6] + r[7]));
    }
    __syncthreads();
    if (tid < 32) xnorm[b * 1024 + hw0 + tid] = H[tid][0] + H[tid][1];
    {   // convert (scaled fp16): thread -> (row, 64-d segment)
        int row = tid >> 2, seg = tid & 3;
        const float* src = &T[row][seg * 64];
        unsigned short* dst = A_hi + ((size_t)(b * 1024 + hw0 + row) * 256 + seg * 64);
        #pragma unroll
        for (int c = 0; c < 8; ++c) {
            unsigned int ub[4];
            #pragma unroll
            for (int p = 0; p < 4; ++p) {
                unsigned int lo = f16_rne(src[c * 8 + 2 * p] * A_SCALE);
                unsigned int hi = f16_rne(src[c * 8 + 2 * p + 1] * A_SCALE);
                ub[p] = lo | (hi << 16);
            }
            *(uint4*)(dst + c * 8) = make_uint4(ub[0], ub[1], ub[2], ub[3]);
        }
    }
}

// ---- emb-prep: np-pairwise enorm + B_hi fp16(e*4096) + embT fp32 (d-major) ----
__launch_bounds__(256)
__global__ void emb_prep_kernel(const float* __restrict__ emb,
                                float* __restrict__ enorm,
                                unsigned short* __restrict__ B_hi,
                                float* __restrict__ embT) {
#pragma clang fp contract(off)
    const int k = blockIdx.x * 256 + threadIdx.x;
    const float* p = emb + (size_t)k * D_DIM;
    float half[2];
    #pragma unroll
    for (int h = 0; h < 2; ++h) {
        const float* q = p + h * 128;
        float r[8];
        #pragma unroll
        for (int j = 0; j < 8; ++j) { float x = q[j]; r[j] = x * x; }
        for (int i = 8; i < 128; i += 8)
            #pragma unroll
            for (int j = 0; j < 8; ++j) { float x = q[i + j]; r[j] = r[j] + x * x; }
        half[h] = ((r[0] + r[1]) + (r[2] + r[3])) + ((r[4] + r[5]) + (r[6] + r[7]));
    }
    enorm[k] = half[0] + half[1];
    unsigned int* dst = (unsigned int*)(B_hi + (size_t)k * D_DIM);
    for (int d = 0; d < 128; ++d) {
        unsigned int lo = f16_rne(p[2 * d] * B_SCALE);
        unsigned int hi = f16_rne(p[2 * d + 1] * B_SCALE);
        dst[d] = lo | (hi << 16);
    }
    for (int d = 0; d < D_DIM; ++d)            // coalesced: consecutive k per lane
        embT[(size_t)d * K_CODES + k] = p[d];
}

// ---- dist2: fp16 MFMA, 128 rows x ALL 1024 codes per block ----
// LDS: As 64KB (persistent, swizzled granules) | Bs 8KB (streamed per (cb,s)).
// Swizzle: global k-granule q of row r stored at LDS granule q^((r>>1)&3)
// (involution). Fragment reads then hit 2-way bank aliasing (free) instead of
// 8-way. Staging realizes the swizzle by pre-swizzling the per-lane GLOBAL
// source (LDS dest of global_load_lds is always base+lane*16, rule #21).
__launch_bounds__(256, 2)
__global__ void dist2_kernel(const unsigned short* __restrict__ A_hi,
                             const unsigned short* __restrict__ B_hi,
                             const float* __restrict__ xnorm,
                             const float* __restrict__ enorm,
                             int* __restrict__ fidx,
                             int* __restrict__ amb,
                             int* __restrict__ amb_count) {
    __shared__ __align__(16) char smem[73728];            // As 64KB | Bs 8KB
    unsigned long long* red = (unsigned long long*)(smem + 65536); // overlay on Bs

    const int tid  = threadIdx.x;
    const int lane = tid & 63, w = tid >> 6;
    const int quad = lane >> 4, l16 = lane & 15;
    const int wr = w >> 1, wc = w & 1;
    const int row0 = blockIdx.x * 128;

    // per-lane staging constants: lane covers (row = base + lane/4, granule lane&3)
    // and fetches the global granule that belongs at that LDS slot (inverse swizzle)
    const int aq    = (((lane & 3) ^ ((lane >> 3) & 3)) << 3);  // shorts
    const int arsub = (w << 4) + (lane >> 2);
    // per-lane read swizzle: granule (quad ^ ((l16>>1)&3)) of the fragment row
    const int rdoff = ((quad ^ ((l16 >> 1) & 3)) << 4);         // bytes

    // ---- stage A tile: 128 rows x 256 k = 64KB, 16 issues/thread ----
    #pragma unroll
    for (int t = 0; t < 16; ++t) {
        const int arow = ((t & 1) << 6) + arsub;
        const int s    = t >> 1;
        gld16(A_hi + (((size_t)(row0 + arow)) << 8) + s * 32 + aq,
              smem + t * 4096 + w * 1024);
    }

    // ---- per-thread state ----
    float xnr[4][4];
    #pragma unroll
    for (int i = 0; i < 4; ++i)
        #pragma unroll
        for (int r = 0; r < 4; ++r)
            xnr[i][r] = xnorm[row0 + wr * 64 + i * 16 + quad * 4 + r];

    unsigned long long p1[4][4], p2[4][4];
    #pragma unroll
    for (int i = 0; i < 4; ++i)
        #pragma unroll
        for (int r = 0; r < 4; ++r) { p1[i][r] = ~0ull; p2[i][r] = ~0ull; }

    // ---- main loop: cb over 8 code-chunks of 128, s over 8 K-steps of 32 ----
    for (int cb = 0; cb < 8; ++cb) {
        f32x4 acc[4][4];
        #pragma unroll
        for (int i = 0; i < 4; ++i)
            #pragma unroll
            for (int j = 0; j < 4; ++j) acc[i][j] = (f32x4){0.f, 0.f, 0.f, 0.f};

        for (int s = 0; s < 8; ++s) {
            __syncthreads();     // Bs reads of previous step complete
            gld16(B_hi + (((size_t)(cb * 128 + arsub)) << 8) + s * 32 + aq,
                  smem + 65536 + w * 1024);
            gld16(B_hi + (((size_t)(cb * 128 + 64 + arsub)) << 8) + s * 32 + aq,
                  smem + 65536 + 4096 + w * 1024);
            __syncthreads();     // staging complete (vmcnt drain at barrier)

            half8 af[4], bf[4];
            #pragma unroll
            for (int i = 0; i < 4; ++i)
                af[i] = *(const half8*)(smem + s * 8192 + (wr * 64 + i * 16 + l16) * 64 + rdoff);
            #pragma unroll
            for (int j = 0; j < 4; ++j)
                bf[j] = *(const half8*)(smem + 65536 + (wc * 64 + j * 16 + l16) * 64 + rdoff);
            #pragma unroll
            for (int i = 0; i < 4; ++i)
                #pragma unroll
                for (int j = 0; j < 4; ++j)
                    acc[i][j] = __builtin_amdgcn_mfma_f32_16x16x32_f16(af[i], bf[j], acc[i][j], 0, 0, 0);
        }

        // fold this code-chunk into the running per-lane top-2 (no reduce here)
        float enj[4];
        #pragma unroll
        for (int j = 0; j < 4; ++j) enj[j] = enorm[cb * 128 + wc * 64 + j * 16 + l16];
        #pragma unroll
        for (int i = 0; i < 4; ++i) {
            #pragma unroll
            for (int r = 0; r < 4; ++r) {
                float xn = xnr[i][r];
                unsigned long long a1 = p1[i][r], a2 = p2[i][r];
                #pragma unroll
                for (int j = 0; j < 4; ++j) {
                    int n = cb * 128 + wc * 64 + j * 16 + l16;
                    float sc = (xn + enj[j]) - acc[i][j][r] * INV_SCALE2;
                    unsigned long long p = ((unsigned long long)mono(sc) << 32) | (unsigned int)n;
                    if (p < a1) { a2 = a1; a1 = p; } else if (p < a2) a2 = p;
                }
                p1[i][r] = a1; p2[i][r] = a2;
            }
        }
    }

    // ---- one reduce per row: 16-lane shfl + wc merge in LDS ----
    __syncthreads();             // last Bs reads done before red overlay
    #pragma unroll
    for (int i = 0; i < 4; ++i) {
        #pragma unroll
        for (int r = 0; r < 4; ++r) {
            unsigned long long a1 = p1[i][r], a2 = p2[i][r];
            #pragma unroll
            for (int m = 1; m < 16; m <<= 1) {
                unsigned long long q1 = __shfl_xor(a1, m, 16);
                unsigned long long q2 = __shfl_xor(a2, m, 16);
                if (q1 < a1) { a2 = (a1 < q2) ? a1 : q2; a1 = q1; }
                else         { a2 = (a2 < q1) ? a2 : q1; }
            }
            if (l16 == 0) {
                int rowl = wr * 64 + i * 16 + quad * 4 + r;
                red[(rowl * 2 + wc) * 2 + 0] = a1;
                red[(rowl * 2 + wc) * 2 + 1] = a2;
            }
        }
    }
    __syncthreads();
    if (tid < 128) {
        unsigned long long a1 = red[(tid * 2 + 0) * 2 + 0];
        unsigned long long a2 = red[(tid * 2 + 0) * 2 + 1];
        unsigned long long b1 = red[(tid * 2 + 1) * 2 + 0];
        unsigned long long b2 = red[(tid * 2 + 1) * 2 + 1];
        if (b1 < a1) { a2 = (a1 < b2) ? a1 : b2; a1 = b1; }
        else         { a2 = (a2 < b1) ? a2 : b1; }
        const int row = row0 + tid;
        fidx[row] = (int)(a1 & 0xFFFFFFFFull);
        float s1 = unmono((unsigned int)(a1 >> 32));
        float s2 = unmono((unsigned int)(a2 >> 32));
        if (s2 - s1 <= FLAG_MARGIN) {
            int slot = atomicAdd(amb_count, 1);
            if (slot < AMB_CAP) amb[slot] = row;
        }
    }
}

// ---- rescue (4 rows/group): thread owns 4 consecutive codes x 4 rows.
// acc = 16 doubles = 32 VGPRs, all statically indexed (full unroll) -> registers.
// Per-(code,row) accumulation order over d is IDENTICAL to rounds 8-10.
__launch_bounds__(256)
__global__ void rescue4_kernel(const float* __restrict__ z_e,
                               const float* __restrict__ embT,
                               const float* __restrict__ xnorm,
                               const float* __restrict__ enorm,
                               const int* __restrict__ amb,
                               const int* __restrict__ amb_count,
                               int* __restrict__ fidx) {
    __shared__ float xs[4][256];
    __shared__ int rows[4];
    __shared__ unsigned long long pm[4][257];
    const int tid = threadIdx.x;
    int cnt = *amb_count;
    if (cnt > AMB_CAP) cnt = AMB_CAP;
    if (cnt <= 0) return;
    const int ngroups = (cnt + 3) >> 2;
    for (int g = blockIdx.x; g < ngroups; g += gridDim.x) {
        if (tid < 4) {
            int e = g * 4 + tid;
            rows[tid] = amb[e < cnt ? e : (cnt - 1)];   // pad with dup (benign)
        }
        __syncthreads();
        {   // stage x rows: thread -> (row j, 4 d-elements)
            const int j = tid >> 6, d0 = (tid & 63) * 4;
            const int row = rows[j];
            const int b = row >> 10, hw = row & 1023;
            const float* zp = z_e + (size_t)b * 262144 + hw;
            #pragma unroll
            for (int i = 0; i < 4; ++i)
                xs[j][d0 + i] = zp[(size_t)(d0 + i) * 1024];
        }
        __syncthreads();

        double acc[4][4];                       // [code c][row j], static idx only
        #pragma unroll
        for (int c = 0; c < 4; ++c)
            #pragma unroll
            for (int j = 0; j < 4; ++j) acc[c][j] = 0.0;

        const float* ep = embT + 4 * tid;
        #pragma unroll 2
        for (int d = 0; d < D_DIM; ++d) {
            float4 ev = *(const float4*)(ep + (size_t)d * K_CODES);
            double e0 = (double)ev.x, e1 = (double)ev.y;
            double e2 = (double)ev.z, e3 = (double)ev.w;
            double x0 = (double)xs[0][d], x1 = (double)xs[1][d];
            double x2 = (double)xs[2][d], x3 = (double)xs[3][d];
            acc[0][0] += x0 * e0; acc[0][1] += x1 * e0; acc[0][2] += x2 * e0; acc[0][3] += x3 * e0;
            acc[1][0] += x0 * e1; acc[1][1] += x1 * e1; acc[1][2] += x2 * e1; acc[1][3] += x3 * e1;
            acc[2][0] += x0 * e2; acc[2][1] += x1 * e2; acc[2][2] += x2 * e2; acc[2][3] += x3 * e2;
            acc[3][0] += x0 * e3; acc[3][1] += x1 * e3; acc[3][2] += x2 * e3; acc[3][3] += x3 * e3;
        }

        float xnr[4];
        #pragma unroll
        for (int j = 0; j < 4; ++j) xnr[j] = xnorm[rows[j]];

        unsigned long long mm[4] = {~0ull, ~0ull, ~0ull, ~0ull};
        #pragma unroll
        for (int c = 0; c < 4; ++c) {
            const int k = 4 * tid + c;
            const float en = enorm[k];
            #pragma unroll
            for (int j = 0; j < 4; ++j) {
                float dv = (float)acc[c][j];
                float t = xnr[j] + en;
                float s = t - 2.f * dv;
                unsigned long long p = ((unsigned long long)mono(s) << 32) | (unsigned int)k;
                if (p < mm[j]) mm[j] = p;
            }
        }
        #pragma unroll
        for (int j = 0; j < 4; ++j) pm[j][tid] = mm[j];
        __syncthreads();
        for (int s = 128; s > 0; s >>= 1) {
            if (tid < s) {
                #pragma unroll
                for (int j = 0; j < 4; ++j)
                    if (pm[j][tid + s] < pm[j][tid]) pm[j][tid] = pm[j][tid + s];
            }
            __syncthreads();
        }
        if (tid < 4) fidx[rows[tid]] = (int)(pm[tid][0] & 0xFFFFFFFFull);
        __syncthreads();
    }
}

__global__ void epilogue_kernel(const float* __restrict__ z_e,
                                const float* __restrict__ emb,
                                const int* __restrict__ fidx,
                                float* __restrict__ out,
                                int* __restrict__ counts,
                                float* __restrict__ loss_sum) {
    __shared__ int   kb[64];
    __shared__ float rs[256];
    const int tid = threadIdx.x;
    const int rcb = blockIdx.x;
    const int b   = rcb >> 4;
    const int hw0 = (rcb & 15) << 6;

    if (tid < 64) {
        int k = fidx[rcb * 64 + tid];
        kb[tid] = k;
        out[(size_t)IDX_OFF + (size_t)rcb * 64 + tid] = (float)k;
        atomicAdd(&counts[k], 1);
    }
    __syncthreads();

    const int j = tid & 63, dq = tid >> 6;
    const float* er = emb + (size_t)kb[j] * D_DIM;
    const size_t base = (size_t)b * 262144 + hw0 + j;
    float ls = 0.f;
    #pragma unroll 4
    for (int d = dq; d < D_DIM; d += 4) {
        float zq = er[d];
        size_t off = base + (size_t)d * 1024;
        float x = z_e[off];
        out[off] = zq;
        float df = zq - x;
        ls += df * df;
    }
    rs[tid] = ls;
    __syncthreads();
    for (int s = 128; s > 0; s >>= 1) {
        if (tid < s) rs[tid] += rs[tid + s];
        __syncthreads();
    }
    if (tid == 0) atomicAdd(loss_sum, rs[0]);
}

__global__ void finalize_kernel(const int* __restrict__ counts,
                                const float* __restrict__ loss_sum,
                                float* __restrict__ out) {
    __shared__ float rs[256];
    const int tid = threadIdx.x;
    float s = 0.f;
    for (int k = tid; k < K_CODES; k += 256) {
        float p = (float)counts[k] / 65536.0f;
        s += p * logf(p + 1e-10f);
    }
    rs[tid] = s;
    __syncthreads();
    for (int st = 128; st > 0; st >>= 1) {
        if (tid < st) rs[tid] += rs[tid + st];
        __syncthreads();
    }
    if (tid == 0) {
        out[N_ELEM]     = loss_sum[0] * 1.25f / 16777216.0f;
        out[N_ELEM + 1] = expf(-rs[0]);
    }
}

extern "C" void kernel_launch(void* const* d_in, const int* in_sizes, int n_in,
                              void* d_out, int out_size, void* d_ws, size_t ws_size,
                              hipStream_t stream) {
    const float* z_e = (const float*)d_in[0];
    const float* emb = (const float*)d_in[1];
    float* out = (float*)d_out;
    char*  ws  = (char*)d_ws;

    // big scratch inside d_out (overwritten by epilogue)
    unsigned short* A_hi = (unsigned short*)d_out;

    float*          enorm    = (float*)ws;
    float*          xnorm    = (float*)(ws + 4096);
    int*            fidx     = (int*)(ws + 266240);
    int*            counts   = (int*)(ws + 528384);
    float*          loss_sum = (float*)(ws + 532480);
    int*            amb_cnt  = (int*)(ws + 532484);
    int*            amb      = (int*)(ws + 532488);
    unsigned short* B_hi     = (unsigned short*)(ws + 794752);
    float*          embT     = (float*)(ws + 1319040);

    hipMemsetAsync(counts, 0, 4104, stream);   // counts + loss_sum + amb_count

    a_prep_kernel<<<2048, 128, 0, stream>>>(z_e, A_hi, xnorm);
    emb_prep_kernel<<<K_CODES / 256, 256, 0, stream>>>(emb, enorm, B_hi, embT);
    dist2_kernel<<<512, 256, 0, stream>>>(A_hi, B_hi, xnorm, enorm, fidx, amb, amb_cnt);
    rescue4_kernel<<<1024, 256, 0, stream>>>(z_e, embT, xnorm, enorm, amb, amb_cnt, fidx);
    epilogue_kernel<<<N_ROWS / 64, 256, 0, stream>>>(z_e, emb, fidx, out, counts, loss_sum);
    finalize_kernel<<<1, 256, 0, stream>>>(counts, loss_sum, out);
}

// Round 4
// 327.214 us; speedup vs baseline: 1.3924x; 1.0886x over previous
//
#include <hip/hip_runtime.h>
#include <hip/hip_fp16.h>
#include <stdint.h>

// VQ-VAE forward on MI355X — fp16-MFMA fast path + fp64 rescue for exact np argmin.
// Round 12: dist2 pipeline fixes. Round-11 counters: MfmaUtil 11.8, VALUBusy 27,
// bank-conflicts ~0 -> ~60% stall. Cause: 2 barriers per 8KB B-chunk (128 total),
// each draining vmcnt(0) on loads issued immediately prior (zero hiding, only 2
// blocks/CU). Changes: (1) double-buffered Bs (LDS 64+2x8=80KB, still 2 blocks/CU),
// prefetch next chunk BEFORE computing current -> ONE __syncthreads per K-step
// (64 barriers), drain lands after ~ds_read+16 MFMA of cover. (2) top-2 insert
// cheapened from ~14 VALU (u64 cmp/cndmask chain) to ~6 (float online top-2 +
// 1 cndmask argmin idx); u64 mono-pack only at the final 16-lane reduce.
// Semantics: exact fp32 value ties -> m1==m2 -> gap<=margin -> rescue (as before);
// strict < keeps lowest index per lane (n ascending per lane); reduce merge
// unchanged. Rescue/prep kernels untouched.
//
// z_e: [64, 256, 32, 32] f32 ; emb: [1024, 256] f32
// out: z_q_st (16777216) | loss (1) | perplexity (1) | idx (65536, as float)
//
// Big scratch in d_out's z_q region (overwritten by epilogue last):
//   out bytes [0, 32MB)       A_hi  fp16[65536][256]  (transposed z_e, x16)
// ws layout (bytes):
//   [0,      4096)    enorm f32[1024]      [4096,   266240)  xnorm f32[65536]
//   [266240, 528384)  fidx  i32[65536]     [528384, 532480)  counts i32[1024]
//   [532480, 532484)  loss_sum             [532484, 532488)  amb_count
//   [532488, 794632)  amb i32[65536]
//   [794752, 1319040) B_hi fp16[1024][256] (e*4096)
//   [1319040,2367616) embT f32[256][1024]

#define D_DIM   256
#define K_CODES 1024
#define N_ROWS  65536
#define N_ELEM  16777216
#define IDX_OFF 16777218
#define FLAG_MARGIN 1.5e-4f
#define AMB_CAP 65536
#define A_SCALE 16.0f
#define B_SCALE 4096.0f
#define INV_SCALE2 3.0517578125e-05f   /* 2 / (16*4096) = 2^-15, exact */

typedef short short8 __attribute__((ext_vector_type(8)));
typedef _Float16 half8 __attribute__((ext_vector_type(8)));
typedef float f32x4  __attribute__((ext_vector_type(4)));

__device__ __forceinline__ unsigned int mono(float s) {
    unsigned int u = __float_as_uint(s);
    return (u & 0x80000000u) ? ~u : (u | 0x80000000u);
}
__device__ __forceinline__ float unmono(unsigned int u) {
    return __uint_as_float((u & 0x80000000u) ? (u & 0x7FFFFFFFu) : ~u);
}
__device__ __forceinline__ unsigned short f16_rne(float x) {
    return __half_as_ushort(__float2half(x));   // RNE
}
__device__ __forceinline__ void gld16(const void* g, void* l) {
    __builtin_amdgcn_global_load_lds(
        (const __attribute__((address_space(1))) unsigned int*)g,
        (__attribute__((address_space(3))) unsigned int*)l, 16, 0, 0);
}

// ---- A-prep: transpose z_e -> A_hi fp16(x*16) row-major; np-pairwise xnorm ----
__launch_bounds__(128)
__global__ void a_prep_kernel(const float* __restrict__ z_e,
                              unsigned short* __restrict__ A_hi,
                              float* __restrict__ xnorm) {
#pragma clang fp contract(off)
    __shared__ float T[32][257];
    __shared__ float H[32][2];
    const int tid = threadIdx.x;
    const int bx = blockIdx.x;                 // 2048 blocks
    const int b = bx >> 5, hw0 = (bx & 31) << 5;
    const float* zb = z_e + (size_t)b * 262144 + hw0;
    #pragma unroll 4
    for (int it = 0; it < 16; ++it) {
        int flat = it * 128 + tid;             // 2048 float4
        int d = flat >> 3;
        int hw4 = (flat & 7) << 2;
        float4 v = *(const float4*)(zb + (size_t)d * 1024 + hw4);
        T[hw4 + 0][d] = v.x; T[hw4 + 1][d] = v.y;
        T[hw4 + 2][d] = v.z; T[hw4 + 3][d] = v.w;
    }
    __syncthreads();
    if (tid < 64) {                            // np pairwise tree per 128-half
        int row = tid >> 1, h = tid & 1;
        const float* q = &T[row][h * 128];
        float r[8];
        #pragma unroll
        for (int j = 0; j < 8; ++j) { float x = q[j]; r[j] = x * x; }
        for (int i = 8; i < 128; i += 8)
            #pragma unroll
            for (int j = 0; j < 8; ++j) { float x = q[i + j]; r[j] = r[j] + x * x; }
        H[row][h] = ((r[0] + r[1]) + (r[2] + r[3])) + ((r[4] + r[5]) + (r[6] + r[7]));
    }
    __syncthreads();
    if (tid < 32) xnorm[b * 1024 + hw0 + tid] = H[tid][0] + H[tid][1];
    {   // convert (scaled fp16): thread -> (row, 64-d segment)
        int row = tid >> 2, seg = tid & 3;
        const float* src = &T[row][seg * 64];
        unsigned short* dst = A_hi + ((size_t)(b * 1024 + hw0 + row) * 256 + seg * 64);
        #pragma unroll
        for (int c = 0; c < 8; ++c) {
            unsigned int ub[4];
            #pragma unroll
            for (int p = 0; p < 4; ++p) {
                unsigned int lo = f16_rne(src[c * 8 + 2 * p] * A_SCALE);
                unsigned int hi = f16_rne(src[c * 8 + 2 * p + 1] * A_SCALE);
                ub[p] = lo | (hi << 16);
            }
            *(uint4*)(dst + c * 8) = make_uint4(ub[0], ub[1], ub[2], ub[3]);
        }
    }
}

// ---- emb-prep: np-pairwise enorm + B_hi fp16(e*4096) + embT fp32 (d-major) ----
__launch_bounds__(256)
__global__ void emb_prep_kernel(const float* __restrict__ emb,
                                float* __restrict__ enorm,
                                unsigned short* __restrict__ B_hi,
                                float* __restrict__ embT) {
#pragma clang fp contract(off)
    const int k = blockIdx.x * 256 + threadIdx.x;
    const float* p = emb + (size_t)k * D_DIM;
    float half[2];
    #pragma unroll
    for (int h = 0; h < 2; ++h) {
        const float* q = p + h * 128;
        float r[8];
        #pragma unroll
        for (int j = 0; j < 8; ++j) { float x = q[j]; r[j] = x * x; }
        for (int i = 8; i < 128; i += 8)
            #pragma unroll
            for (int j = 0; j < 8; ++j) { float x = q[i + j]; r[j] = r[j] + x * x; }
        half[h] = ((r[0] + r[1]) + (r[2] + r[3])) + ((r[4] + r[5]) + (r[6] + r[7]));
    }
    enorm[k] = half[0] + half[1];
    unsigned int* dst = (unsigned int*)(B_hi + (size_t)k * D_DIM);
    for (int d = 0; d < 128; ++d) {
        unsigned int lo = f16_rne(p[2 * d] * B_SCALE);
        unsigned int hi = f16_rne(p[2 * d + 1] * B_SCALE);
        dst[d] = lo | (hi << 16);
    }
    for (int d = 0; d < D_DIM; ++d)            // coalesced: consecutive k per lane
        embT[(size_t)d * K_CODES + k] = p[d];
}

// ---- dist2: fp16 MFMA, 128 rows x ALL 1024 codes per block ----
// LDS: As 64KB (persistent, swizzled granules) | Bs 2x8KB double-buffer.
// One __syncthreads per K-step: prefetch next chunk into buf^1, compute from
// buf, barrier (auto vmcnt(0) drain covers loads issued a full compute-phase
// earlier). Swizzle as round 11 (granule q^((r>>1)&3), involution, 2-way free).
__launch_bounds__(256, 2)
__global__ void dist2_kernel(const unsigned short* __restrict__ A_hi,
                             const unsigned short* __restrict__ B_hi,
                             const float* __restrict__ xnorm,
                             const float* __restrict__ enorm,
                             int* __restrict__ fidx,
                             int* __restrict__ amb,
                             int* __restrict__ amb_count) {
    __shared__ __align__(16) char smem[81920];            // As 64KB | Bs 2x8KB
    unsigned long long* red = (unsigned long long*)(smem + 65536); // overlay buf0

    const int tid  = threadIdx.x;
    const int lane = tid & 63, w = tid >> 6;
    const int quad = lane >> 4, l16 = lane & 15;
    const int wr = w >> 1, wc = w & 1;
    const int row0 = blockIdx.x * 128;

    // per-lane staging constants: lane covers (row = base + lane/4, granule lane&3)
    // fetching the global granule that belongs at that LDS slot (inverse swizzle)
    const int aq    = (((lane & 3) ^ ((lane >> 3) & 3)) << 3);  // shorts
    const int arsub = (w << 4) + (lane >> 2);
    // per-lane read swizzle: granule (quad ^ ((l16>>1)&3)) of the fragment row
    const int rdoff = ((quad ^ ((l16 >> 1) & 3)) << 4);         // bytes

    // ---- prologue: stage A tile (64KB) + B chunk 0 ----
    #pragma unroll
    for (int t = 0; t < 16; ++t) {
        const int arow = ((t & 1) << 6) + arsub;
        const int s    = t >> 1;
        gld16(A_hi + (((size_t)(row0 + arow)) << 8) + s * 32 + aq,
              smem + t * 4096 + w * 1024);
    }
    gld16(B_hi + (((size_t)(arsub)) << 8) + aq,       smem + 65536 + w * 1024);
    gld16(B_hi + (((size_t)(64 + arsub)) << 8) + aq,  smem + 65536 + 4096 + w * 1024);
    __syncthreads();

    // ---- per-thread state ----
    float xnr[4][4];
    #pragma unroll
    for (int i = 0; i < 4; ++i)
        #pragma unroll
        for (int r = 0; r < 4; ++r)
            xnr[i][r] = xnorm[row0 + wr * 64 + i * 16 + quad * 4 + r];

    const float INF = __uint_as_float(0x7F800000u);
    float m1[4][4], m2[4][4];
    unsigned int ix[4][4];
    #pragma unroll
    for (int i = 0; i < 4; ++i)
        #pragma unroll
        for (int r = 0; r < 4; ++r) { m1[i][r] = INF; m2[i][r] = INF; ix[i][r] = 0u; }

    int cur = 0;
    // ---- main loop: cb over 8 code-chunks of 128, s over 8 K-steps of 32 ----
    for (int cb = 0; cb < 8; ++cb) {
        f32x4 acc[4][4];
        #pragma unroll
        for (int i = 0; i < 4; ++i)
            #pragma unroll
            for (int j = 0; j < 4; ++j) acc[i][j] = (f32x4){0.f, 0.f, 0.f, 0.f};

        for (int s = 0; s < 8; ++s) {
            // prefetch next chunk into the other buffer (hidden under compute)
            const int nstep = cb * 8 + s + 1;
            if (nstep < 64) {
                const int ncb = nstep >> 3, ns = nstep & 7;
                char* nb = smem + 65536 + ((cur ^ 1) << 13);
                gld16(B_hi + (((size_t)(ncb * 128 + arsub)) << 8) + ns * 32 + aq,
                      nb + w * 1024);
                gld16(B_hi + (((size_t)(ncb * 128 + 64 + arsub)) << 8) + ns * 32 + aq,
                      nb + 4096 + w * 1024);
            }
            const char* bb = smem + 65536 + (cur << 13);
            half8 af[4], bf[4];
            #pragma unroll
            for (int i = 0; i < 4; ++i)
                af[i] = *(const half8*)(smem + s * 8192 + (wr * 64 + i * 16 + l16) * 64 + rdoff);
            #pragma unroll
            for (int j = 0; j < 4; ++j)
                bf[j] = *(const half8*)(bb + (wc * 64 + j * 16 + l16) * 64 + rdoff);
            #pragma unroll
            for (int i = 0; i < 4; ++i)
                #pragma unroll
                for (int j = 0; j < 4; ++j)
                    acc[i][j] = __builtin_amdgcn_mfma_f32_16x16x32_f16(af[i], bf[j], acc[i][j], 0, 0, 0);
            __syncthreads();     // drains prefetch (issued ~ds_read+MFMA ago) + read fences
            cur ^= 1;
        }

        // fold this code-chunk into running float top-2 + argmin idx (cheap insert)
        float enj[4];
        #pragma unroll
        for (int j = 0; j < 4; ++j) enj[j] = enorm[cb * 128 + wc * 64 + j * 16 + l16];
        #pragma unroll
        for (int i = 0; i < 4; ++i) {
            #pragma unroll
            for (int r = 0; r < 4; ++r) {
                const float xn = xnr[i][r];
                float a = m1[i][r], b = m2[i][r];
                unsigned int id = ix[i][r];
                #pragma unroll
                for (int j = 0; j < 4; ++j) {
                    const unsigned int n = cb * 128 + wc * 64 + j * 16 + l16;
                    float sc = fmaf(acc[i][j][r], -INV_SCALE2, xn + enj[j]);
                    bool c = sc < a;
                    b = fminf(b, fmaxf(a, sc));
                    a = fminf(a, sc);
                    id = c ? n : id;
                }
                m1[i][r] = a; m2[i][r] = b; ix[i][r] = id;
            }
        }
    }

    // ---- one reduce per row: u64 pack at reduce time, 16-lane shfl + wc merge ----
    // (all LDS reads completed at the loop's final barrier; red overlays buf area)
    #pragma unroll
    for (int i = 0; i < 4; ++i) {
        #pragma unroll
        for (int r = 0; r < 4; ++r) {
            unsigned long long a1 = ((unsigned long long)mono(m1[i][r]) << 32) | ix[i][r];
            unsigned long long a2 = ((unsigned long long)mono(m2[i][r]) << 32) | 0xFFFFFFFFull;
            #pragma unroll
            for (int m = 1; m < 16; m <<= 1) {
                unsigned long long q1 = __shfl_xor(a1, m, 16);
                unsigned long long q2 = __shfl_xor(a2, m, 16);
                if (q1 < a1) { a2 = (a1 < q2) ? a1 : q2; a1 = q1; }
                else         { a2 = (a2 < q1) ? a2 : q1; }
            }
            if (l16 == 0) {
                int rowl = wr * 64 + i * 16 + quad * 4 + r;
                red[(rowl * 2 + wc) * 2 + 0] = a1;
                red[(rowl * 2 + wc) * 2 + 1] = a2;
            }
        }
    }
    __syncthreads();
    if (tid < 128) {
        unsigned long long a1 = red[(tid * 2 + 0) * 2 + 0];
        unsigned long long a2 = red[(tid * 2 + 0) * 2 + 1];
        unsigned long long b1 = red[(tid * 2 + 1) * 2 + 0];
        unsigned long long b2 = red[(tid * 2 + 1) * 2 + 1];
        if (b1 < a1) { a2 = (a1 < b2) ? a1 : b2; a1 = b1; }
        else         { a2 = (a2 < b1) ? a2 : b1; }
        const int row = row0 + tid;
        fidx[row] = (int)(a1 & 0xFFFFFFFFull);
        float s1 = unmono((unsigned int)(a1 >> 32));
        float s2 = unmono((unsigned int)(a2 >> 32));
        if (s2 - s1 <= FLAG_MARGIN) {
            int slot = atomicAdd(amb_count, 1);
            if (slot < AMB_CAP) amb[slot] = row;
        }
    }
}

// ---- rescue (4 rows/group): thread owns 4 consecutive codes x 4 rows.
// acc = 16 doubles = 32 VGPRs, all statically indexed (full unroll) -> registers.
// Per-(code,row) accumulation order over d is IDENTICAL to rounds 8-11.
__launch_bounds__(256)
__global__ void rescue4_kernel(const float* __restrict__ z_e,
                               const float* __restrict__ embT,
                               const float* __restrict__ xnorm,
                               const float* __restrict__ enorm,
                               const int* __restrict__ amb,
                               const int* __restrict__ amb_count,
                               int* __restrict__ fidx) {
    __shared__ float xs[4][256];
    __shared__ int rows[4];
    __shared__ unsigned long long pm[4][257];
    const int tid = threadIdx.x;
    int cnt = *amb_count;
    if (cnt > AMB_CAP) cnt = AMB_CAP;
    if (cnt <= 0) return;
    const int ngroups = (cnt + 3) >> 2;
    for (int g = blockIdx.x; g < ngroups; g += gridDim.x) {
        if (tid < 4) {
            int e = g * 4 + tid;
            rows[tid] = amb[e < cnt ? e : (cnt - 1)];   // pad with dup (benign)
        }
        __syncthreads();
        {   // stage x rows: thread -> (row j, 4 d-elements)
            const int j = tid >> 6, d0 = (tid & 63) * 4;
            const int row = rows[j];
            const int b = row >> 10, hw = row & 1023;
            const float* zp = z_e + (size_t)b * 262144 + hw;
            #pragma unroll
            for (int i = 0; i < 4; ++i)
                xs[j][d0 + i] = zp[(size_t)(d0 + i) * 1024];
        }
        __syncthreads();

        double acc[4][4];                       // [code c][row j], static idx only
        #pragma unroll
        for (int c = 0; c < 4; ++c)
            #pragma unroll
            for (int j = 0; j < 4; ++j) acc[c][j] = 0.0;

        const float* ep = embT + 4 * tid;
        #pragma unroll 2
        for (int d = 0; d < D_DIM; ++d) {
            float4 ev = *(const float4*)(ep + (size_t)d * K_CODES);
            double e0 = (double)ev.x, e1 = (double)ev.y;
            double e2 = (double)ev.z, e3 = (double)ev.w;
            double x0 = (double)xs[0][d], x1 = (double)xs[1][d];
            double x2 = (double)xs[2][d], x3 = (double)xs[3][d];
            acc[0][0] += x0 * e0; acc[0][1] += x1 * e0; acc[0][2] += x2 * e0; acc[0][3] += x3 * e0;
            acc[1][0] += x0 * e1; acc[1][1] += x1 * e1; acc[1][2] += x2 * e1; acc[1][3] += x3 * e1;
            acc[2][0] += x0 * e2; acc[2][1] += x1 * e2; acc[2][2] += x2 * e2; acc[2][3] += x3 * e2;
            acc[3][0] += x0 * e3; acc[3][1] += x1 * e3; acc[3][2] += x2 * e3; acc[3][3] += x3 * e3;
        }

        float xnr[4];
        #pragma unroll
        for (int j = 0; j < 4; ++j) xnr[j] = xnorm[rows[j]];

        unsigned long long mm[4] = {~0ull, ~0ull, ~0ull, ~0ull};
        #pragma unroll
        for (int c = 0; c < 4; ++c) {
            const int k = 4 * tid + c;
            const float en = enorm[k];
            #pragma unroll
            for (int j = 0; j < 4; ++j) {
                float dv = (float)acc[c][j];
                float t = xnr[j] + en;
                float s = t - 2.f * dv;
                unsigned long long p = ((unsigned long long)mono(s) << 32) | (unsigned int)k;
                if (p < mm[j]) mm[j] = p;
            }
        }
        #pragma unroll
        for (int j = 0; j < 4; ++j) pm[j][tid] = mm[j];
        __syncthreads();
        for (int s = 128; s > 0; s >>= 1) {
            if (tid < s) {
                #pragma unroll
                for (int j = 0; j < 4; ++j)
                    if (pm[j][tid + s] < pm[j][tid]) pm[j][tid] = pm[j][tid + s];
            }
            __syncthreads();
        }
        if (tid < 4) fidx[rows[tid]] = (int)(pm[tid][0] & 0xFFFFFFFFull);
        __syncthreads();
    }
}

__global__ void epilogue_kernel(const float* __restrict__ z_e,
                                const float* __restrict__ emb,
                                const int* __restrict__ fidx,
                                float* __restrict__ out,
                                int* __restrict__ counts,
                                float* __restrict__ loss_sum) {
    __shared__ int   kb[64];
    __shared__ float rs[256];
    const int tid = threadIdx.x;
    const int rcb = blockIdx.x;
    const int b   = rcb >> 4;
    const int hw0 = (rcb & 15) << 6;

    if (tid < 64) {
        int k = fidx[rcb * 64 + tid];
        kb[tid] = k;
        out[(size_t)IDX_OFF + (size_t)rcb * 64 + tid] = (float)k;
        atomicAdd(&counts[k], 1);
    }
    __syncthreads();

    const int j = tid & 63, dq = tid >> 6;
    const float* er = emb + (size_t)kb[j] * D_DIM;
    const size_t base = (size_t)b * 262144 + hw0 + j;
    float ls = 0.f;
    #pragma unroll 4
    for (int d = dq; d < D_DIM; d += 4) {
        float zq = er[d];
        size_t off = base + (size_t)d * 1024;
        float x = z_e[off];
        out[off] = zq;
        float df = zq - x;
        ls += df * df;
    }
    rs[tid] = ls;
    __syncthreads();
    for (int s = 128; s > 0; s >>= 1) {
        if (tid < s) rs[tid] += rs[tid + s];
        __syncthreads();
    }
    if (tid == 0) atomicAdd(loss_sum, rs[0]);
}

__global__ void finalize_kernel(const int* __restrict__ counts,
                                const float* __restrict__ loss_sum,
                                float* __restrict__ out) {
    __shared__ float rs[256];
    const int tid = threadIdx.x;
    float s = 0.f;
    for (int k = tid; k < K_CODES; k += 256) {
        float p = (float)counts[k] / 65536.0f;
        s += p * logf(p + 1e-10f);
    }
    rs[tid] = s;
    __syncthreads();
    for (int st = 128; st > 0; st >>= 1) {
        if (tid < st) rs[tid] += rs[tid + st];
        __syncthreads();
    }
    if (tid == 0) {
        out[N_ELEM]     = loss_sum[0] * 1.25f / 16777216.0f;
        out[N_ELEM + 1] = expf(-rs[0]);
    }
}

extern "C" void kernel_launch(void* const* d_in, const int* in_sizes, int n_in,
                              void* d_out, int out_size, void* d_ws, size_t ws_size,
                              hipStream_t stream) {
    const float* z_e = (const float*)d_in[0];
    const float* emb = (const float*)d_in[1];
    float* out = (float*)d_out;
    char*  ws  = (char*)d_ws;

    // big scratch inside d_out (overwritten by epilogue)
    unsigned short* A_hi = (unsigned short*)d_out;

    float*          enorm    = (float*)ws;
    float*          xnorm    = (float*)(ws + 4096);
    int*            fidx     = (int*)(ws + 266240);
    int*            counts   = (int*)(ws + 528384);
    float*          loss_sum = (float*)(ws + 532480);
    int*            amb_cnt  = (int*)(ws + 532484);
    int*            amb      = (int*)(ws + 532488);
    unsigned short* B_hi     = (unsigned short*)(ws + 794752);
    float*          embT     = (float*)(ws + 1319040);

    hipMemsetAsync(counts, 0, 4104, stream);   // counts + loss_sum + amb_count

    a_prep_kernel<<<2048, 128, 0, stream>>>(z_e, A_hi, xnorm);
    emb_prep_kernel<<<K_CODES / 256, 256, 0, stream>>>(emb, enorm, B_hi, embT);
    dist2_kernel<<<512, 256, 0, stream>>>(A_hi, B_hi, xnorm, enorm, fidx, amb, amb_cnt);
    rescue4_kernel<<<1024, 256, 0, stream>>>(z_e, embT, xnorm, enorm, amb, amb_cnt, fidx);
    epilogue_kernel<<<N_ROWS / 64, 256, 0, stream>>>(z_e, emb, fidx, out, counts, loss_sum);
    finalize_kernel<<<1, 256, 0, stream>>>(counts, loss_sum, out);
}

// Round 5
// 322.304 us; speedup vs baseline: 1.4136x; 1.0152x over previous
//
#include <hip/hip_runtime.h>
#include <hip/hip_fp16.h>
#include <stdint.h>

// VQ-VAE forward on MI355X — fp16-MFMA fast path + fp64 rescue for exact np argmin.
// Round 13: (1) rescue d-loop software-pipelined at depth 8 (ev[8] float4 batch
// then 128 FMAs). Round-12 counters: rescue=59us with VGPR=48 -> unroll-2 gave
// only 2 outstanding L2 loads; one group per block means duration IS the
// single-group latency, so ILP (not cnt, not grouping) is the lever. fp64 add
// order per acc chain unchanged (ascending d) -> bit-identical rescue results.
// (2) epilogue vectorized along hw: thread -> (4-hw float4, 16 d-slices);
// 16B/lane coalesced z_e/out traffic; per-lane emb gather = 4 scalar L2 hits.
// Loss partial-sum grouping changes (reorder noise ~1e-6, within tolerance).
//
// z_e: [64, 256, 32, 32] f32 ; emb: [1024, 256] f32
// out: z_q_st (16777216) | loss (1) | perplexity (1) | idx (65536, as float)
//
// Big scratch in d_out's z_q region (overwritten by epilogue last):
//   out bytes [0, 32MB)       A_hi  fp16[65536][256]  (transposed z_e, x16)
// ws layout (bytes):
//   [0,      4096)    enorm f32[1024]      [4096,   266240)  xnorm f32[65536]
//   [266240, 528384)  fidx  i32[65536]     [528384, 532480)  counts i32[1024]
//   [532480, 532484)  loss_sum             [532484, 532488)  amb_count
//   [532488, 794632)  amb i32[65536]
//   [794752, 1319040) B_hi fp16[1024][256] (e*4096)
//   [1319040,2367616) embT f32[256][1024]

#define D_DIM   256
#define K_CODES 1024
#define N_ROWS  65536
#define N_ELEM  16777216
#define IDX_OFF 16777218
#define FLAG_MARGIN 1.5e-4f
#define AMB_CAP 65536
#define A_SCALE 16.0f
#define B_SCALE 4096.0f
#define INV_SCALE2 3.0517578125e-05f   /* 2 / (16*4096) = 2^-15, exact */

typedef short short8 __attribute__((ext_vector_type(8)));
typedef _Float16 half8 __attribute__((ext_vector_type(8)));
typedef float f32x4  __attribute__((ext_vector_type(4)));

__device__ __forceinline__ unsigned int mono(float s) {
    unsigned int u = __float_as_uint(s);
    return (u & 0x80000000u) ? ~u : (u | 0x80000000u);
}
__device__ __forceinline__ float unmono(unsigned int u) {
    return __uint_as_float((u & 0x80000000u) ? (u & 0x7FFFFFFFu) : ~u);
}
__device__ __forceinline__ unsigned short f16_rne(float x) {
    return __half_as_ushort(__float2half(x));   // RNE
}
__device__ __forceinline__ void gld16(const void* g, void* l) {
    __builtin_amdgcn_global_load_lds(
        (const __attribute__((address_space(1))) unsigned int*)g,
        (__attribute__((address_space(3))) unsigned int*)l, 16, 0, 0);
}

// ---- A-prep: transpose z_e -> A_hi fp16(x*16) row-major; np-pairwise xnorm ----
__launch_bounds__(128)
__global__ void a_prep_kernel(const float* __restrict__ z_e,
                              unsigned short* __restrict__ A_hi,
                              float* __restrict__ xnorm) {
#pragma clang fp contract(off)
    __shared__ float T[32][257];
    __shared__ float H[32][2];
    const int tid = threadIdx.x;
    const int bx = blockIdx.x;                 // 2048 blocks
    const int b = bx >> 5, hw0 = (bx & 31) << 5;
    const float* zb = z_e + (size_t)b * 262144 + hw0;
    #pragma unroll 4
    for (int it = 0; it < 16; ++it) {
        int flat = it * 128 + tid;             // 2048 float4
        int d = flat >> 3;
        int hw4 = (flat & 7) << 2;
        float4 v = *(const float4*)(zb + (size_t)d * 1024 + hw4);
        T[hw4 + 0][d] = v.x; T[hw4 + 1][d] = v.y;
        T[hw4 + 2][d] = v.z; T[hw4 + 3][d] = v.w;
    }
    __syncthreads();
    if (tid < 64) {                            // np pairwise tree per 128-half
        int row = tid >> 1, h = tid & 1;
        const float* q = &T[row][h * 128];
        float r[8];
        #pragma unroll
        for (int j = 0; j < 8; ++j) { float x = q[j]; r[j] = x * x; }
        for (int i = 8; i < 128; i += 8)
            #pragma unroll
            for (int j = 0; j < 8; ++j) { float x = q[i + j]; r[j] = r[j] + x * x; }
        H[row][h] = ((r[0] + r[1]) + (r[2] + r[3])) + ((r[4] + r[5]) + (r[6] + r[7]));
    }
    __syncthreads();
    if (tid < 32) xnorm[b * 1024 + hw0 + tid] = H[tid][0] + H[tid][1];
    {   // convert (scaled fp16): thread -> (row, 64-d segment)
        int row = tid >> 2, seg = tid & 3;
        const float* src = &T[row][seg * 64];
        unsigned short* dst = A_hi + ((size_t)(b * 1024 + hw0 + row) * 256 + seg * 64);
        #pragma unroll
        for (int c = 0; c < 8; ++c) {
            unsigned int ub[4];
            #pragma unroll
            for (int p = 0; p < 4; ++p) {
                unsigned int lo = f16_rne(src[c * 8 + 2 * p] * A_SCALE);
                unsigned int hi = f16_rne(src[c * 8 + 2 * p + 1] * A_SCALE);
                ub[p] = lo | (hi << 16);
            }
            *(uint4*)(dst + c * 8) = make_uint4(ub[0], ub[1], ub[2], ub[3]);
        }
    }
}

// ---- emb-prep: np-pairwise enorm + B_hi fp16(e*4096) + embT fp32 (d-major) ----
__launch_bounds__(256)
__global__ void emb_prep_kernel(const float* __restrict__ emb,
                                float* __restrict__ enorm,
                                unsigned short* __restrict__ B_hi,
                                float* __restrict__ embT) {
#pragma clang fp contract(off)
    const int k = blockIdx.x * 256 + threadIdx.x;
    const float* p = emb + (size_t)k * D_DIM;
    float half[2];
    #pragma unroll
    for (int h = 0; h < 2; ++h) {
        const float* q = p + h * 128;
        float r[8];
        #pragma unroll
        for (int j = 0; j < 8; ++j) { float x = q[j]; r[j] = x * x; }
        for (int i = 8; i < 128; i += 8)
            #pragma unroll
            for (int j = 0; j < 8; ++j) { float x = q[i + j]; r[j] = r[j] + x * x; }
        half[h] = ((r[0] + r[1]) + (r[2] + r[3])) + ((r[4] + r[5]) + (r[6] + r[7]));
    }
    enorm[k] = half[0] + half[1];
    unsigned int* dst = (unsigned int*)(B_hi + (size_t)k * D_DIM);
    for (int d = 0; d < 128; ++d) {
        unsigned int lo = f16_rne(p[2 * d] * B_SCALE);
        unsigned int hi = f16_rne(p[2 * d + 1] * B_SCALE);
        dst[d] = lo | (hi << 16);
    }
    for (int d = 0; d < D_DIM; ++d)            // coalesced: consecutive k per lane
        embT[(size_t)d * K_CODES + k] = p[d];
}

// ---- dist2: fp16 MFMA, 128 rows x ALL 1024 codes per block ----
// LDS: As 64KB (persistent, swizzled granules) | Bs 2x8KB double-buffer.
// One __syncthreads per K-step: prefetch next chunk into buf^1, compute from
// buf, barrier (auto vmcnt(0) drain covers loads issued a full compute-phase
// earlier). Swizzle as round 11 (granule q^((r>>1)&3), involution, 2-way free).
__launch_bounds__(256, 2)
__global__ void dist2_kernel(const unsigned short* __restrict__ A_hi,
                             const unsigned short* __restrict__ B_hi,
                             const float* __restrict__ xnorm,
                             const float* __restrict__ enorm,
                             int* __restrict__ fidx,
                             int* __restrict__ amb,
                             int* __restrict__ amb_count) {
    __shared__ __align__(16) char smem[81920];            // As 64KB | Bs 2x8KB
    unsigned long long* red = (unsigned long long*)(smem + 65536); // overlay buf0

    const int tid  = threadIdx.x;
    const int lane = tid & 63, w = tid >> 6;
    const int quad = lane >> 4, l16 = lane & 15;
    const int wr = w >> 1, wc = w & 1;
    const int row0 = blockIdx.x * 128;

    // per-lane staging constants: lane covers (row = base + lane/4, granule lane&3)
    // fetching the global granule that belongs at that LDS slot (inverse swizzle)
    const int aq    = (((lane & 3) ^ ((lane >> 3) & 3)) << 3);  // shorts
    const int arsub = (w << 4) + (lane >> 2);
    // per-lane read swizzle: granule (quad ^ ((l16>>1)&3)) of the fragment row
    const int rdoff = ((quad ^ ((l16 >> 1) & 3)) << 4);         // bytes

    // ---- prologue: stage A tile (64KB) + B chunk 0 ----
    #pragma unroll
    for (int t = 0; t < 16; ++t) {
        const int arow = ((t & 1) << 6) + arsub;
        const int s    = t >> 1;
        gld16(A_hi + (((size_t)(row0 + arow)) << 8) + s * 32 + aq,
              smem + t * 4096 + w * 1024);
    }
    gld16(B_hi + (((size_t)(arsub)) << 8) + aq,       smem + 65536 + w * 1024);
    gld16(B_hi + (((size_t)(64 + arsub)) << 8) + aq,  smem + 65536 + 4096 + w * 1024);
    __syncthreads();

    // ---- per-thread state ----
    float xnr[4][4];
    #pragma unroll
    for (int i = 0; i < 4; ++i)
        #pragma unroll
        for (int r = 0; r < 4; ++r)
            xnr[i][r] = xnorm[row0 + wr * 64 + i * 16 + quad * 4 + r];

    const float INF = __uint_as_float(0x7F800000u);
    float m1[4][4], m2[4][4];
    unsigned int ix[4][4];
    #pragma unroll
    for (int i = 0; i < 4; ++i)
        #pragma unroll
        for (int r = 0; r < 4; ++r) { m1[i][r] = INF; m2[i][r] = INF; ix[i][r] = 0u; }

    int cur = 0;
    // ---- main loop: cb over 8 code-chunks of 128, s over 8 K-steps of 32 ----
    for (int cb = 0; cb < 8; ++cb) {
        f32x4 acc[4][4];
        #pragma unroll
        for (int i = 0; i < 4; ++i)
            #pragma unroll
            for (int j = 0; j < 4; ++j) acc[i][j] = (f32x4){0.f, 0.f, 0.f, 0.f};

        for (int s = 0; s < 8; ++s) {
            // prefetch next chunk into the other buffer (hidden under compute)
            const int nstep = cb * 8 + s + 1;
            if (nstep < 64) {
                const int ncb = nstep >> 3, ns = nstep & 7;
                char* nb = smem + 65536 + ((cur ^ 1) << 13);
                gld16(B_hi + (((size_t)(ncb * 128 + arsub)) << 8) + ns * 32 + aq,
                      nb + w * 1024);
                gld16(B_hi + (((size_t)(ncb * 128 + 64 + arsub)) << 8) + ns * 32 + aq,
                      nb + 4096 + w * 1024);
            }
            const char* bb = smem + 65536 + (cur << 13);
            half8 af[4], bf[4];
            #pragma unroll
            for (int i = 0; i < 4; ++i)
                af[i] = *(const half8*)(smem + s * 8192 + (wr * 64 + i * 16 + l16) * 64 + rdoff);
            #pragma unroll
            for (int j = 0; j < 4; ++j)
                bf[j] = *(const half8*)(bb + (wc * 64 + j * 16 + l16) * 64 + rdoff);
            #pragma unroll
            for (int i = 0; i < 4; ++i)
                #pragma unroll
                for (int j = 0; j < 4; ++j)
                    acc[i][j] = __builtin_amdgcn_mfma_f32_16x16x32_f16(af[i], bf[j], acc[i][j], 0, 0, 0);
            __syncthreads();     // drains prefetch (issued ~ds_read+MFMA ago) + read fences
            cur ^= 1;
        }

        // fold this code-chunk into running float top-2 + argmin idx (cheap insert)
        float enj[4];
        #pragma unroll
        for (int j = 0; j < 4; ++j) enj[j] = enorm[cb * 128 + wc * 64 + j * 16 + l16];
        #pragma unroll
        for (int i = 0; i < 4; ++i) {
            #pragma unroll
            for (int r = 0; r < 4; ++r) {
                const float xn = xnr[i][r];
                float a = m1[i][r], b = m2[i][r];
                unsigned int id = ix[i][r];
                #pragma unroll
                for (int j = 0; j < 4; ++j) {
                    const unsigned int n = cb * 128 + wc * 64 + j * 16 + l16;
                    float sc = fmaf(acc[i][j][r], -INV_SCALE2, xn + enj[j]);
                    bool c = sc < a;
                    b = fminf(b, fmaxf(a, sc));
                    a = fminf(a, sc);
                    id = c ? n : id;
                }
                m1[i][r] = a; m2[i][r] = b; ix[i][r] = id;
            }
        }
    }

    // ---- one reduce per row: u64 pack at reduce time, 16-lane shfl + wc merge ----
    // (all LDS reads completed at the loop's final barrier; red overlays buf area)
    #pragma unroll
    for (int i = 0; i < 4; ++i) {
        #pragma unroll
        for (int r = 0; r < 4; ++r) {
            unsigned long long a1 = ((unsigned long long)mono(m1[i][r]) << 32) | ix[i][r];
            unsigned long long a2 = ((unsigned long long)mono(m2[i][r]) << 32) | 0xFFFFFFFFull;
            #pragma unroll
            for (int m = 1; m < 16; m <<= 1) {
                unsigned long long q1 = __shfl_xor(a1, m, 16);
                unsigned long long q2 = __shfl_xor(a2, m, 16);
                if (q1 < a1) { a2 = (a1 < q2) ? a1 : q2; a1 = q1; }
                else         { a2 = (a2 < q1) ? a2 : q1; }
            }
            if (l16 == 0) {
                int rowl = wr * 64 + i * 16 + quad * 4 + r;
                red[(rowl * 2 + wc) * 2 + 0] = a1;
                red[(rowl * 2 + wc) * 2 + 1] = a2;
            }
        }
    }
    __syncthreads();
    if (tid < 128) {
        unsigned long long a1 = red[(tid * 2 + 0) * 2 + 0];
        unsigned long long a2 = red[(tid * 2 + 0) * 2 + 1];
        unsigned long long b1 = red[(tid * 2 + 1) * 2 + 0];
        unsigned long long b2 = red[(tid * 2 + 1) * 2 + 1];
        if (b1 < a1) { a2 = (a1 < b2) ? a1 : b2; a1 = b1; }
        else         { a2 = (a2 < b1) ? a2 : b1; }
        const int row = row0 + tid;
        fidx[row] = (int)(a1 & 0xFFFFFFFFull);
        float s1 = unmono((unsigned int)(a1 >> 32));
        float s2 = unmono((unsigned int)(a2 >> 32));
        if (s2 - s1 <= FLAG_MARGIN) {
            int slot = atomicAdd(amb_count, 1);
            if (slot < AMB_CAP) amb[slot] = row;
        }
    }
}

// ---- rescue (4 rows/group): thread owns 4 consecutive codes x 4 rows.
// Round 13: d-loop software-pipelined depth 8 — ev[8] float4 batch-load then
// 128 fp64 FMAs (round-12: VGPR=48 capped ILP at 2 outstanding loads; one group
// per block means duration == single-group latency -> ILP is the only lever).
// Per-(code,row) fp64 add order still ascending d -> bit-identical results.
__launch_bounds__(256)
__global__ void rescue4_kernel(const float* __restrict__ z_e,
                               const float* __restrict__ embT,
                               const float* __restrict__ xnorm,
                               const float* __restrict__ enorm,
                               const int* __restrict__ amb,
                               const int* __restrict__ amb_count,
                               int* __restrict__ fidx) {
    __shared__ float xs[4][256];
    __shared__ int rows[4];
    __shared__ unsigned long long pm[4][257];
    const int tid = threadIdx.x;
    int cnt = *amb_count;
    if (cnt > AMB_CAP) cnt = AMB_CAP;
    if (cnt <= 0) return;
    const int ngroups = (cnt + 3) >> 2;
    for (int g = blockIdx.x; g < ngroups; g += gridDim.x) {
        if (tid < 4) {
            int e = g * 4 + tid;
            rows[tid] = amb[e < cnt ? e : (cnt - 1)];   // pad with dup (benign)
        }
        __syncthreads();
        {   // stage x rows: thread -> (row j, 4 d-elements)
            const int j = tid >> 6, d0 = (tid & 63) * 4;
            const int row = rows[j];
            const int b = row >> 10, hw = row & 1023;
            const float* zp = z_e + (size_t)b * 262144 + hw;
            #pragma unroll
            for (int i = 0; i < 4; ++i)
                xs[j][d0 + i] = zp[(size_t)(d0 + i) * 1024];
        }
        __syncthreads();

        double acc[4][4];                       // [code c][row j], static idx only
        #pragma unroll
        for (int c = 0; c < 4; ++c)
            #pragma unroll
            for (int j = 0; j < 4; ++j) acc[c][j] = 0.0;

        const float* ep = embT + 4 * tid;
        for (int d0 = 0; d0 < D_DIM; d0 += 8) {
            float4 ev[8];
            #pragma unroll
            for (int u = 0; u < 8; ++u)
                ev[u] = *(const float4*)(ep + (size_t)(d0 + u) * K_CODES);
            #pragma unroll
            for (int u = 0; u < 8; ++u) {
                const int d = d0 + u;
                double e0 = (double)ev[u].x, e1 = (double)ev[u].y;
                double e2 = (double)ev[u].z, e3 = (double)ev[u].w;
                double x0 = (double)xs[0][d], x1 = (double)xs[1][d];
                double x2 = (double)xs[2][d], x3 = (double)xs[3][d];
                acc[0][0] += x0 * e0; acc[0][1] += x1 * e0; acc[0][2] += x2 * e0; acc[0][3] += x3 * e0;
                acc[1][0] += x0 * e1; acc[1][1] += x1 * e1; acc[1][2] += x2 * e1; acc[1][3] += x3 * e1;
                acc[2][0] += x0 * e2; acc[2][1] += x1 * e2; acc[2][2] += x2 * e2; acc[2][3] += x3 * e2;
                acc[3][0] += x0 * e3; acc[3][1] += x1 * e3; acc[3][2] += x2 * e3; acc[3][3] += x3 * e3;
            }
        }

        float xnr[4];
        #pragma unroll
        for (int j = 0; j < 4; ++j) xnr[j] = xnorm[rows[j]];

        unsigned long long mm[4] = {~0ull, ~0ull, ~0ull, ~0ull};
        #pragma unroll
        for (int c = 0; c < 4; ++c) {
            const int k = 4 * tid + c;
            const float en = enorm[k];
            #pragma unroll
            for (int j = 0; j < 4; ++j) {
                float dv = (float)acc[c][j];
                float t = xnr[j] + en;
                float s = t - 2.f * dv;
                unsigned long long p = ((unsigned long long)mono(s) << 32) | (unsigned int)k;
                if (p < mm[j]) mm[j] = p;
            }
        }
        #pragma unroll
        for (int j = 0; j < 4; ++j) pm[j][tid] = mm[j];
        __syncthreads();
        for (int s = 128; s > 0; s >>= 1) {
            if (tid < s) {
                #pragma unroll
                for (int j = 0; j < 4; ++j)
                    if (pm[j][tid + s] < pm[j][tid]) pm[j][tid] = pm[j][tid + s];
            }
            __syncthreads();
        }
        if (tid < 4) fidx[rows[tid]] = (int)(pm[tid][0] & 0xFFFFFFFFull);
        __syncthreads();
    }
}

// ---- epilogue: hw-vectorized (16B/lane). thread -> (4-hw float4, 16 d-slices).
// Loss partial-sum grouping differs from round 12 (reorder noise ~1e-6).
__global__ void epilogue_kernel(const float* __restrict__ z_e,
                                const float* __restrict__ emb,
                                const int* __restrict__ fidx,
                                float* __restrict__ out,
                                int* __restrict__ counts,
                                float* __restrict__ loss_sum) {
    __shared__ int   kb[64];
    __shared__ float rs[256];
    const int tid = threadIdx.x;
    const int rcb = blockIdx.x;
    const int b   = rcb >> 4;
    const int hw0 = (rcb & 15) << 6;

    if (tid < 64) {
        int k = fidx[rcb * 64 + tid];
        kb[tid] = k;
        out[(size_t)IDX_OFF + (size_t)rcb * 64 + tid] = (float)k;
        atomicAdd(&counts[k], 1);
    }
    __syncthreads();

    const int j4 = (tid & 15) << 2;   // hw offset within the 64-chunk, float4
    const int dq = tid >> 4;          // 16 d-slices
    const float* e0 = emb + (size_t)kb[j4 + 0] * D_DIM;
    const float* e1 = emb + (size_t)kb[j4 + 1] * D_DIM;
    const float* e2 = emb + (size_t)kb[j4 + 2] * D_DIM;
    const float* e3 = emb + (size_t)kb[j4 + 3] * D_DIM;
    const size_t base = (size_t)b * 262144 + hw0 + j4;
    float ls = 0.f;
    #pragma unroll 4
    for (int d = dq; d < D_DIM; d += 16) {
        size_t off = base + ((size_t)d << 10);
        float4 x = *(const float4*)(z_e + off);
        float4 q;
        q.x = e0[d]; q.y = e1[d]; q.z = e2[d]; q.w = e3[d];
        *(float4*)(out + off) = q;
        float d0 = q.x - x.x, d1 = q.y - x.y, d2 = q.z - x.z, d3 = q.w - x.w;
        ls += d0 * d0; ls += d1 * d1; ls += d2 * d2; ls += d3 * d3;
    }
    rs[tid] = ls;
    __syncthreads();
    for (int s = 128; s > 0; s >>= 1) {
        if (tid < s) rs[tid] += rs[tid + s];
        __syncthreads();
    }
    if (tid == 0) atomicAdd(loss_sum, rs[0]);
}

__global__ void finalize_kernel(const int* __restrict__ counts,
                                const float* __restrict__ loss_sum,
                                float* __restrict__ out) {
    __shared__ float rs[256];
    const int tid = threadIdx.x;
    float s = 0.f;
    for (int k = tid; k < K_CODES; k += 256) {
        float p = (float)counts[k] / 65536.0f;
        s += p * logf(p + 1e-10f);
    }
    rs[tid] = s;
    __syncthreads();
    for (int st = 128; st > 0; st >>= 1) {
        if (tid < st) rs[tid] += rs[tid + st];
        __syncthreads();
    }
    if (tid == 0) {
        out[N_ELEM]     = loss_sum[0] * 1.25f / 16777216.0f;
        out[N_ELEM + 1] = expf(-rs[0]);
    }
}

extern "C" void kernel_launch(void* const* d_in, const int* in_sizes, int n_in,
                              void* d_out, int out_size, void* d_ws, size_t ws_size,
                              hipStream_t stream) {
    const float* z_e = (const float*)d_in[0];
    const float* emb = (const float*)d_in[1];
    float* out = (float*)d_out;
    char*  ws  = (char*)d_ws;

    // big scratch inside d_out (overwritten by epilogue)
    unsigned short* A_hi = (unsigned short*)d_out;

    float*          enorm    = (float*)ws;
    float*          xnorm    = (float*)(ws + 4096);
    int*            fidx     = (int*)(ws + 266240);
    int*            counts   = (int*)(ws + 528384);
    float*          loss_sum = (float*)(ws + 532480);
    int*            amb_cnt  = (int*)(ws + 532484);
    int*            amb      = (int*)(ws + 532488);
    unsigned short* B_hi     = (unsigned short*)(ws + 794752);
    float*          embT     = (float*)(ws + 1319040);

    hipMemsetAsync(counts, 0, 4104, stream);   // counts + loss_sum + amb_count

    a_prep_kernel<<<2048, 128, 0, stream>>>(z_e, A_hi, xnorm);
    emb_prep_kernel<<<K_CODES / 256, 256, 0, stream>>>(emb, enorm, B_hi, embT);
    dist2_kernel<<<512, 256, 0, stream>>>(A_hi, B_hi, xnorm, enorm, fidx, amb, amb_cnt);
    rescue4_kernel<<<1024, 256, 0, stream>>>(z_e, embT, xnorm, enorm, amb, amb_cnt, fidx);
    epilogue_kernel<<<N_ROWS / 64, 256, 0, stream>>>(z_e, emb, fidx, out, counts, loss_sum);
    finalize_kernel<<<1, 256, 0, stream>>>(counts, loss_sum, out);
}

// Round 6
// 281.750 us; speedup vs baseline: 1.6171x; 1.1439x over previous
//
#include <hip/hip_runtime.h>
#include <hip/hip_fp16.h>
#include <stdint.h>

// VQ-VAE forward on MI355X — fp16-MFMA fast path + fp64 rescue for exact np argmin.
// Round 14: pipeline-level fixes. Round-13 counters: dist2=56us is only 17% of
// the 322us total; ~250us is in never-profiled kernels. emb_prep ran FOUR blocks
// (1024 threads, 0.4% of GPU, ~640 serialized uncoalesced ops/thread) fully
// serialized in the stream -> fused into prep_kernel (emb blocks 0-3 dispatch
// first, hide under 2048 a-blocks; rows register-batched float4 for ILP; enorm
// np-pairwise tree arithmetic-identical). memset dispatch dropped (prep zeros
// counts/loss_sum/amb_count). a-part widened to 256 threads (same values).
// dist2: s_setprio around MFMA cluster (T5). 7 -> 5 dispatches.
//
// z_e: [64, 256, 32, 32] f32 ; emb: [1024, 256] f32
// out: z_q_st (16777216) | loss (1) | perplexity (1) | idx (65536, as float)
//
// Big scratch in d_out's z_q region (overwritten by epilogue last):
//   out bytes [0, 32MB)       A_hi  fp16[65536][256]  (transposed z_e, x16)
// ws layout (bytes):
//   [0,      4096)    enorm f32[1024]      [4096,   266240)  xnorm f32[65536]
//   [266240, 528384)  fidx  i32[65536]     [528384, 532480)  counts i32[1024]
//   [532480, 532484)  loss_sum             [532484, 532488)  amb_count
//   [532488, 794632)  amb i32[65536]
//   [794752, 1319040) B_hi fp16[1024][256] (e*4096)
//   [1319040,2367616) embT f32[256][1024]

#define D_DIM   256
#define K_CODES 1024
#define N_ROWS  65536
#define N_ELEM  16777216
#define IDX_OFF 16777218
#define FLAG_MARGIN 1.5e-4f
#define AMB_CAP 65536
#define A_SCALE 16.0f
#define B_SCALE 4096.0f
#define INV_SCALE2 3.0517578125e-05f   /* 2 / (16*4096) = 2^-15, exact */

typedef short short8 __attribute__((ext_vector_type(8)));
typedef _Float16 half8 __attribute__((ext_vector_type(8)));
typedef float f32x4  __attribute__((ext_vector_type(4)));

__device__ __forceinline__ unsigned int mono(float s) {
    unsigned int u = __float_as_uint(s);
    return (u & 0x80000000u) ? ~u : (u | 0x80000000u);
}
__device__ __forceinline__ float unmono(unsigned int u) {
    return __uint_as_float((u & 0x80000000u) ? (u & 0x7FFFFFFFu) : ~u);
}
__device__ __forceinline__ unsigned short f16_rne(float x) {
    return __half_as_ushort(__float2half(x));   // RNE
}
__device__ __forceinline__ void gld16(const void* g, void* l) {
    __builtin_amdgcn_global_load_lds(
        (const __attribute__((address_space(1))) unsigned int*)g,
        (__attribute__((address_space(3))) unsigned int*)l, 16, 0, 0);
}

// ---- fused prep: blocks 0-3 = emb path (enorm/B_hi/embT + zero counters);
//      blocks 4..2051 = z_e transpose -> A_hi fp16(x16) + xnorm ----
__launch_bounds__(256)
__global__ void prep_kernel(const float* __restrict__ z_e,
                            const float* __restrict__ emb,
                            unsigned short* __restrict__ A_hi,
                            float* __restrict__ xnorm,
                            float* __restrict__ enorm,
                            unsigned short* __restrict__ B_hi,
                            float* __restrict__ embT,
                            int* __restrict__ counts,
                            float* __restrict__ loss_sum,
                            int* __restrict__ amb_count) {
#pragma clang fp contract(off)
    __shared__ float T[32][257];
    __shared__ float H[32][2];
    const int tid = threadIdx.x;
    const int bid = blockIdx.x;

    if (bid < 4) {
        // ---- emb path: one code per thread, register-batched float4 rows ----
        const int k = bid * 256 + tid;
        counts[k] = 0;
        if (bid == 0 && tid == 0) { *loss_sum = 0.f; *amb_count = 0; }
        const float* p = emb + (size_t)k * D_DIM;
        unsigned int* dstB = (unsigned int*)(B_hi + (size_t)k * D_DIM);
        float halfv[2];
        #pragma unroll
        for (int h = 0; h < 2; ++h) {
            float r[8];
            #pragma unroll
            for (int qq = 0; qq < 2; ++qq) {
                float4 ev[16];
                const float* qb = p + h * 128 + qq * 64;
                #pragma unroll
                for (int m = 0; m < 16; ++m)
                    ev[m] = *(const float4*)(qb + 4 * m);
                // np-pairwise: r[j] over ascending i (i = t*8), j in 8-block
                #pragma unroll
                for (int t = 0; t < 8; ++t) {
                    const float4 a = ev[2 * t], b = ev[2 * t + 1];
                    if (qq == 0 && t == 0) {
                        r[0] = a.x * a.x; r[1] = a.y * a.y; r[2] = a.z * a.z; r[3] = a.w * a.w;
                        r[4] = b.x * b.x; r[5] = b.y * b.y; r[6] = b.z * b.z; r[7] = b.w * b.w;
                    } else {
                        r[0] += a.x * a.x; r[1] += a.y * a.y; r[2] += a.z * a.z; r[3] += a.w * a.w;
                        r[4] += b.x * b.x; r[5] += b.y * b.y; r[6] += b.z * b.z; r[7] += b.w * b.w;
                    }
                }
                // B_hi: pack 8 floats (2 float4) -> uint4, sequential d order
                #pragma unroll
                for (int m = 0; m < 16; m += 2) {
                    const float4 a = ev[m], b = ev[m + 1];
                    unsigned int u0 = f16_rne(a.x * B_SCALE) | ((unsigned int)f16_rne(a.y * B_SCALE) << 16);
                    unsigned int u1 = f16_rne(a.z * B_SCALE) | ((unsigned int)f16_rne(a.w * B_SCALE) << 16);
                    unsigned int u2 = f16_rne(b.x * B_SCALE) | ((unsigned int)f16_rne(b.y * B_SCALE) << 16);
                    unsigned int u3 = f16_rne(b.z * B_SCALE) | ((unsigned int)f16_rne(b.w * B_SCALE) << 16);
                    *(uint4*)(dstB + (h * 64 + qq * 32 + 2 * m)) = make_uint4(u0, u1, u2, u3);
                }
                // embT: coalesced across lanes (k per-lane, fixed d per store)
                const int dbase = h * 128 + qq * 64;
                #pragma unroll
                for (int m = 0; m < 16; ++m) {
                    embT[(size_t)(dbase + 4 * m + 0) * K_CODES + k] = ev[m].x;
                    embT[(size_t)(dbase + 4 * m + 1) * K_CODES + k] = ev[m].y;
                    embT[(size_t)(dbase + 4 * m + 2) * K_CODES + k] = ev[m].z;
                    embT[(size_t)(dbase + 4 * m + 3) * K_CODES + k] = ev[m].w;
                }
            }
            halfv[h] = ((r[0] + r[1]) + (r[2] + r[3])) + ((r[4] + r[5]) + (r[6] + r[7]));
        }
        enorm[k] = halfv[0] + halfv[1];
        return;
    }

    // ---- a path: transpose one [32 hw x 256 d] tile ----
    const int bx = bid - 4;                    // 2048 tiles
    const int b = bx >> 5, hw0 = (bx & 31) << 5;
    const float* zb = z_e + (size_t)b * 262144 + hw0;
    #pragma unroll 4
    for (int it = 0; it < 8; ++it) {
        int flat = it * 256 + tid;             // 2048 float4
        int d = flat >> 3;
        int hw4 = (flat & 7) << 2;
        float4 v = *(const float4*)(zb + (size_t)d * 1024 + hw4);
        T[hw4 + 0][d] = v.x; T[hw4 + 1][d] = v.y;
        T[hw4 + 2][d] = v.z; T[hw4 + 3][d] = v.w;
    }
    __syncthreads();
    if (tid < 64) {                            // np pairwise tree per 128-half
        int row = tid >> 1, h = tid & 1;
        const float* q = &T[row][h * 128];
        float r[8];
        #pragma unroll
        for (int j = 0; j < 8; ++j) { float x = q[j]; r[j] = x * x; }
        for (int i = 8; i < 128; i += 8)
            #pragma unroll
            for (int j = 0; j < 8; ++j) { float x = q[i + j]; r[j] = r[j] + x * x; }
        H[row][h] = ((r[0] + r[1]) + (r[2] + r[3])) + ((r[4] + r[5]) + (r[6] + r[7]));
    }
    __syncthreads();
    if (tid < 32) xnorm[b * 1024 + hw0 + tid] = H[tid][0] + H[tid][1];
    {   // convert (scaled fp16): thread -> (row, 32-d segment)
        int row = tid >> 3, seg8 = tid & 7;
        const float* src = &T[row][seg8 * 32];
        unsigned short* dst = A_hi + ((size_t)(b * 1024 + hw0 + row) * 256 + seg8 * 32);
        #pragma unroll
        for (int c = 0; c < 4; ++c) {
            unsigned int ub[4];
            #pragma unroll
            for (int p = 0; p < 4; ++p) {
                unsigned int lo = f16_rne(src[c * 8 + 2 * p] * A_SCALE);
                unsigned int hi = f16_rne(src[c * 8 + 2 * p + 1] * A_SCALE);
                ub[p] = lo | (hi << 16);
            }
            *(uint4*)(dst + c * 8) = make_uint4(ub[0], ub[1], ub[2], ub[3]);
        }
    }
}

// ---- dist2: fp16 MFMA, 128 rows x ALL 1024 codes per block ----
// LDS: As 64KB (persistent, swizzled granules) | Bs 2x8KB double-buffer.
// One __syncthreads per K-step; setprio(1) around the MFMA cluster (T5).
__launch_bounds__(256, 2)
__global__ void dist2_kernel(const unsigned short* __restrict__ A_hi,
                             const unsigned short* __restrict__ B_hi,
                             const float* __restrict__ xnorm,
                             const float* __restrict__ enorm,
                             int* __restrict__ fidx,
                             int* __restrict__ amb,
                             int* __restrict__ amb_count) {
    __shared__ __align__(16) char smem[81920];            // As 64KB | Bs 2x8KB
    unsigned long long* red = (unsigned long long*)(smem + 65536); // overlay buf0

    const int tid  = threadIdx.x;
    const int lane = tid & 63, w = tid >> 6;
    const int quad = lane >> 4, l16 = lane & 15;
    const int wr = w >> 1, wc = w & 1;
    const int row0 = blockIdx.x * 128;

    // per-lane staging constants: lane covers (row = base + lane/4, granule lane&3)
    // fetching the global granule that belongs at that LDS slot (inverse swizzle)
    const int aq    = (((lane & 3) ^ ((lane >> 3) & 3)) << 3);  // shorts
    const int arsub = (w << 4) + (lane >> 2);
    // per-lane read swizzle: granule (quad ^ ((l16>>1)&3)) of the fragment row
    const int rdoff = ((quad ^ ((l16 >> 1) & 3)) << 4);         // bytes

    // ---- prologue: stage A tile (64KB) + B chunk 0 ----
    #pragma unroll
    for (int t = 0; t < 16; ++t) {
        const int arow = ((t & 1) << 6) + arsub;
        const int s    = t >> 1;
        gld16(A_hi + (((size_t)(row0 + arow)) << 8) + s * 32 + aq,
              smem + t * 4096 + w * 1024);
    }
    gld16(B_hi + (((size_t)(arsub)) << 8) + aq,       smem + 65536 + w * 1024);
    gld16(B_hi + (((size_t)(64 + arsub)) << 8) + aq,  smem + 65536 + 4096 + w * 1024);
    __syncthreads();

    // ---- per-thread state ----
    float xnr[4][4];
    #pragma unroll
    for (int i = 0; i < 4; ++i)
        #pragma unroll
        for (int r = 0; r < 4; ++r)
            xnr[i][r] = xnorm[row0 + wr * 64 + i * 16 + quad * 4 + r];

    const float INF = __uint_as_float(0x7F800000u);
    float m1[4][4], m2[4][4];
    unsigned int ix[4][4];
    #pragma unroll
    for (int i = 0; i < 4; ++i)
        #pragma unroll
        for (int r = 0; r < 4; ++r) { m1[i][r] = INF; m2[i][r] = INF; ix[i][r] = 0u; }

    int cur = 0;
    // ---- main loop: cb over 8 code-chunks of 128, s over 8 K-steps of 32 ----
    for (int cb = 0; cb < 8; ++cb) {
        f32x4 acc[4][4];
        #pragma unroll
        for (int i = 0; i < 4; ++i)
            #pragma unroll
            for (int j = 0; j < 4; ++j) acc[i][j] = (f32x4){0.f, 0.f, 0.f, 0.f};

        for (int s = 0; s < 8; ++s) {
            // prefetch next chunk into the other buffer (hidden under compute)
            const int nstep = cb * 8 + s + 1;
            if (nstep < 64) {
                const int ncb = nstep >> 3, ns = nstep & 7;
                char* nb = smem + 65536 + ((cur ^ 1) << 13);
                gld16(B_hi + (((size_t)(ncb * 128 + arsub)) << 8) + ns * 32 + aq,
                      nb + w * 1024);
                gld16(B_hi + (((size_t)(ncb * 128 + 64 + arsub)) << 8) + ns * 32 + aq,
                      nb + 4096 + w * 1024);
            }
            const char* bb = smem + 65536 + (cur << 13);
            half8 af[4], bf[4];
            #pragma unroll
            for (int i = 0; i < 4; ++i)
                af[i] = *(const half8*)(smem + s * 8192 + (wr * 64 + i * 16 + l16) * 64 + rdoff);
            #pragma unroll
            for (int j = 0; j < 4; ++j)
                bf[j] = *(const half8*)(bb + (wc * 64 + j * 16 + l16) * 64 + rdoff);
            __builtin_amdgcn_s_setprio(1);
            #pragma unroll
            for (int i = 0; i < 4; ++i)
                #pragma unroll
                for (int j = 0; j < 4; ++j)
                    acc[i][j] = __builtin_amdgcn_mfma_f32_16x16x32_f16(af[i], bf[j], acc[i][j], 0, 0, 0);
            __builtin_amdgcn_s_setprio(0);
            __syncthreads();     // drains prefetch (issued ~ds_read+MFMA ago) + read fences
            cur ^= 1;
        }

        // fold this code-chunk into running float top-2 + argmin idx (cheap insert)
        float enj[4];
        #pragma unroll
        for (int j = 0; j < 4; ++j) enj[j] = enorm[cb * 128 + wc * 64 + j * 16 + l16];
        #pragma unroll
        for (int i = 0; i < 4; ++i) {
            #pragma unroll
            for (int r = 0; r < 4; ++r) {
                const float xn = xnr[i][r];
                float a = m1[i][r], b = m2[i][r];
                unsigned int id = ix[i][r];
                #pragma unroll
                for (int j = 0; j < 4; ++j) {
                    const unsigned int n = cb * 128 + wc * 64 + j * 16 + l16;
                    float sc = fmaf(acc[i][j][r], -INV_SCALE2, xn + enj[j]);
                    bool c = sc < a;
                    b = fminf(b, fmaxf(a, sc));
                    a = fminf(a, sc);
                    id = c ? n : id;
                }
                m1[i][r] = a; m2[i][r] = b; ix[i][r] = id;
            }
        }
    }

    // ---- one reduce per row: u64 pack at reduce time, 16-lane shfl + wc merge ----
    // (all LDS reads completed at the loop's final barrier; red overlays buf area)
    #pragma unroll
    for (int i = 0; i < 4; ++i) {
        #pragma unroll
        for (int r = 0; r < 4; ++r) {
            unsigned long long a1 = ((unsigned long long)mono(m1[i][r]) << 32) | ix[i][r];
            unsigned long long a2 = ((unsigned long long)mono(m2[i][r]) << 32) | 0xFFFFFFFFull;
            #pragma unroll
            for (int m = 1; m < 16; m <<= 1) {
                unsigned long long q1 = __shfl_xor(a1, m, 16);
                unsigned long long q2 = __shfl_xor(a2, m, 16);
                if (q1 < a1) { a2 = (a1 < q2) ? a1 : q2; a1 = q1; }
                else         { a2 = (a2 < q1) ? a2 : q1; }
            }
            if (l16 == 0) {
                int rowl = wr * 64 + i * 16 + quad * 4 + r;
                red[(rowl * 2 + wc) * 2 + 0] = a1;
                red[(rowl * 2 + wc) * 2 + 1] = a2;
            }
        }
    }
    __syncthreads();
    if (tid < 128) {
        unsigned long long a1 = red[(tid * 2 + 0) * 2 + 0];
        unsigned long long a2 = red[(tid * 2 + 0) * 2 + 1];
        unsigned long long b1 = red[(tid * 2 + 1) * 2 + 0];
        unsigned long long b2 = red[(tid * 2 + 1) * 2 + 1];
        if (b1 < a1) { a2 = (a1 < b2) ? a1 : b2; a1 = b1; }
        else         { a2 = (a2 < b1) ? a2 : b1; }
        const int row = row0 + tid;
        fidx[row] = (int)(a1 & 0xFFFFFFFFull);
        float s1 = unmono((unsigned int)(a1 >> 32));
        float s2 = unmono((unsigned int)(a2 >> 32));
        if (s2 - s1 <= FLAG_MARGIN) {
            int slot = atomicAdd(amb_count, 1);
            if (slot < AMB_CAP) amb[slot] = row;
        }
    }
}

// ---- rescue (4 rows/group): thread owns 4 consecutive codes x 4 rows.
// d-loop software-pipelined depth 8; fp64 add order ascending d (bit-identical).
__launch_bounds__(256)
__global__ void rescue4_kernel(const float* __restrict__ z_e,
                               const float* __restrict__ embT,
                               const float* __restrict__ xnorm,
                               const float* __restrict__ enorm,
                               const int* __restrict__ amb,
                               const int* __restrict__ amb_count,
                               int* __restrict__ fidx) {
    __shared__ float xs[4][256];
    __shared__ int rows[4];
    __shared__ unsigned long long pm[4][257];
    const int tid = threadIdx.x;
    int cnt = *amb_count;
    if (cnt > AMB_CAP) cnt = AMB_CAP;
    if (cnt <= 0) return;
    const int ngroups = (cnt + 3) >> 2;
    for (int g = blockIdx.x; g < ngroups; g += gridDim.x) {
        if (tid < 4) {
            int e = g * 4 + tid;
            rows[tid] = amb[e < cnt ? e : (cnt - 1)];   // pad with dup (benign)
        }
        __syncthreads();
        {   // stage x rows: thread -> (row j, 4 d-elements)
            const int j = tid >> 6, d0 = (tid & 63) * 4;
            const int row = rows[j];
            const int b = row >> 10, hw = row & 1023;
            const float* zp = z_e + (size_t)b * 262144 + hw;
            #pragma unroll
            for (int i = 0; i < 4; ++i)
                xs[j][d0 + i] = zp[(size_t)(d0 + i) * 1024];
        }
        __syncthreads();

        double acc[4][4];                       // [code c][row j], static idx only
        #pragma unroll
        for (int c = 0; c < 4; ++c)
            #pragma unroll
            for (int j = 0; j < 4; ++j) acc[c][j] = 0.0;

        const float* ep = embT + 4 * tid;
        for (int d0 = 0; d0 < D_DIM; d0 += 8) {
            float4 ev[8];
            #pragma unroll
            for (int u = 0; u < 8; ++u)
                ev[u] = *(const float4*)(ep + (size_t)(d0 + u) * K_CODES);
            #pragma unroll
            for (int u = 0; u < 8; ++u) {
                const int d = d0 + u;
                double e0 = (double)ev[u].x, e1 = (double)ev[u].y;
                double e2 = (double)ev[u].z, e3 = (double)ev[u].w;
                double x0 = (double)xs[0][d], x1 = (double)xs[1][d];
                double x2 = (double)xs[2][d], x3 = (double)xs[3][d];
                acc[0][0] += x0 * e0; acc[0][1] += x1 * e0; acc[0][2] += x2 * e0; acc[0][3] += x3 * e0;
                acc[1][0] += x0 * e1; acc[1][1] += x1 * e1; acc[1][2] += x2 * e1; acc[1][3] += x3 * e1;
                acc[2][0] += x0 * e2; acc[2][1] += x1 * e2; acc[2][2] += x2 * e2; acc[2][3] += x3 * e2;
                acc[3][0] += x0 * e3; acc[3][1] += x1 * e3; acc[3][2] += x2 * e3; acc[3][3] += x3 * e3;
            }
        }

        float xnr[4];
        #pragma unroll
        for (int j = 0; j < 4; ++j) xnr[j] = xnorm[rows[j]];

        unsigned long long mm[4] = {~0ull, ~0ull, ~0ull, ~0ull};
        #pragma unroll
        for (int c = 0; c < 4; ++c) {
            const int k = 4 * tid + c;
            const float en = enorm[k];
            #pragma unroll
            for (int j = 0; j < 4; ++j) {
                float dv = (float)acc[c][j];
                float t = xnr[j] + en;
                float s = t - 2.f * dv;
                unsigned long long p = ((unsigned long long)mono(s) << 32) | (unsigned int)k;
                if (p < mm[j]) mm[j] = p;
            }
        }
        #pragma unroll
        for (int j = 0; j < 4; ++j) pm[j][tid] = mm[j];
        __syncthreads();
        for (int s = 128; s > 0; s >>= 1) {
            if (tid < s) {
                #pragma unroll
                for (int j = 0; j < 4; ++j)
                    if (pm[j][tid + s] < pm[j][tid]) pm[j][tid] = pm[j][tid + s];
            }
            __syncthreads();
        }
        if (tid < 4) fidx[rows[tid]] = (int)(pm[tid][0] & 0xFFFFFFFFull);
        __syncthreads();
    }
}

// ---- epilogue: hw-vectorized (16B/lane). thread -> (4-hw float4, 16 d-slices).
__global__ void epilogue_kernel(const float* __restrict__ z_e,
                                const float* __restrict__ emb,
                                const int* __restrict__ fidx,
                                float* __restrict__ out,
                                int* __restrict__ counts,
                                float* __restrict__ loss_sum) {
    __shared__ int   kb[64];
    __shared__ float rs[256];
    const int tid = threadIdx.x;
    const int rcb = blockIdx.x;
    const int b   = rcb >> 4;
    const int hw0 = (rcb & 15) << 6;

    if (tid < 64) {
        int k = fidx[rcb * 64 + tid];
        kb[tid] = k;
        out[(size_t)IDX_OFF + (size_t)rcb * 64 + tid] = (float)k;
        atomicAdd(&counts[k], 1);
    }
    __syncthreads();

    const int j4 = (tid & 15) << 2;   // hw offset within the 64-chunk, float4
    const int dq = tid >> 4;          // 16 d-slices
    const float* e0 = emb + (size_t)kb[j4 + 0] * D_DIM;
    const float* e1 = emb + (size_t)kb[j4 + 1] * D_DIM;
    const float* e2 = emb + (size_t)kb[j4 + 2] * D_DIM;
    const float* e3 = emb + (size_t)kb[j4 + 3] * D_DIM;
    const size_t base = (size_t)b * 262144 + hw0 + j4;
    float ls = 0.f;
    #pragma unroll 4
    for (int d = dq; d < D_DIM; d += 16) {
        size_t off = base + ((size_t)d << 10);
        float4 x = *(const float4*)(z_e + off);
        float4 q;
        q.x = e0[d]; q.y = e1[d]; q.z = e2[d]; q.w = e3[d];
        *(float4*)(out + off) = q;
        float d0 = q.x - x.x, d1 = q.y - x.y, d2 = q.z - x.z, d3 = q.w - x.w;
        ls += d0 * d0; ls += d1 * d1; ls += d2 * d2; ls += d3 * d3;
    }
    rs[tid] = ls;
    __syncthreads();
    for (int s = 128; s > 0; s >>= 1) {
        if (tid < s) rs[tid] += rs[tid + s];
        __syncthreads();
    }
    if (tid == 0) atomicAdd(loss_sum, rs[0]);
}

__global__ void finalize_kernel(const int* __restrict__ counts,
                                const float* __restrict__ loss_sum,
                                float* __restrict__ out) {
    __shared__ float rs[256];
    const int tid = threadIdx.x;
    float s = 0.f;
    for (int k = tid; k < K_CODES; k += 256) {
        float p = (float)counts[k] / 65536.0f;
        s += p * logf(p + 1e-10f);
    }
    rs[tid] = s;
    __syncthreads();
    for (int st = 128; st > 0; st >>= 1) {
        if (tid < st) rs[tid] += rs[tid + st];
        __syncthreads();
    }
    if (tid == 0) {
        out[N_ELEM]     = loss_sum[0] * 1.25f / 16777216.0f;
        out[N_ELEM + 1] = expf(-rs[0]);
    }
}

extern "C" void kernel_launch(void* const* d_in, const int* in_sizes, int n_in,
                              void* d_out, int out_size, void* d_ws, size_t ws_size,
                              hipStream_t stream) {
    const float* z_e = (const float*)d_in[0];
    const float* emb = (const float*)d_in[1];
    float* out = (float*)d_out;
    char*  ws  = (char*)d_ws;

    // big scratch inside d_out (overwritten by epilogue)
    unsigned short* A_hi = (unsigned short*)d_out;

    float*          enorm    = (float*)ws;
    float*          xnorm    = (float*)(ws + 4096);
    int*            fidx     = (int*)(ws + 266240);
    int*            counts   = (int*)(ws + 528384);
    float*          loss_sum = (float*)(ws + 532480);
    int*            amb_cnt  = (int*)(ws + 532484);
    int*            amb      = (int*)(ws + 532488);
    unsigned short* B_hi     = (unsigned short*)(ws + 794752);
    float*          embT     = (float*)(ws + 1319040);

    prep_kernel<<<2052, 256, 0, stream>>>(z_e, emb, A_hi, xnorm, enorm, B_hi, embT,
                                          counts, loss_sum, amb_cnt);
    dist2_kernel<<<512, 256, 0, stream>>>(A_hi, B_hi, xnorm, enorm, fidx, amb, amb_cnt);
    rescue4_kernel<<<1024, 256, 0, stream>>>(z_e, embT, xnorm, enorm, amb, amb_cnt, fidx);
    epilogue_kernel<<<N_ROWS / 64, 256, 0, stream>>>(z_e, emb, fidx, out, counts, loss_sum);
    finalize_kernel<<<1, 256, 0, stream>>>(counts, loss_sum, out);
}